// Round 5
// baseline (160.115 us; speedup 1.0000x reference)
//
#include <hip/hip_runtime.h>
#include <stdint.h>

#define NROWS 8192
#define DDIM 256
#define NPIDS 5532
#define NCQ 5000
#define LCOLS 10532            // NPIDS + NCQ
#define IGNORE_IDX 5554
#define NT 83                  // ceil(10532/128)
#define LPAD (NT * 128)        // 10624
#define NSPLIT 4
#define NPARTS (NSPLIT * 2)    // 8 partial slots per row
#define PADCOLS (LPAD - LCOLS) // 92, each contributes exp2(0)=1 exactly
#define OIM_SCALE 30.0f
#define LOG2E 1.4426950408889634f
#define LN2f 0.6931471805599453f

using f32x4 = __attribute__((ext_vector_type(4))) float;
using bf16x8 = __attribute__((ext_vector_type(8))) __bf16;
using ushort8 = __attribute__((ext_vector_type(8))) unsigned short;
using int4v = __attribute__((ext_vector_type(4))) int;

// ws layout (bytes)
#define WS_INBF 0u             // 8192*256*2   = 4,194,304 (frag-order bf16)
#define WS_BANK 4194304u       // 10624*256*2  = 5,439,488 (frag-order, rse-scaled)
#define WS_PARTS 9633792u      // 8*8192*4     = 262,144
#define WS_RLOGIT 9895936u     // 8192*4       = 32,768
#define WS_BLK 9928704u        // 32*2*4       = 256
#define WS_NEED 9928960u

__device__ __forceinline__ unsigned short f2bf(float f) {
  union { float f; uint32_t u; } v; v.f = f;
  uint32_t u = v.u;
  uint32_t r = (u + 0x7FFFu + ((u >> 16) & 1u)) >> 16;  // RNE
  return (unsigned short)r;
}

// ---------------------------------------------------------------------------
// prep: store A and B in MFMA fragment-consumption order so every main-loop
// operand load is ONE coalesced global_load_dwordx4 (1KB per wave):
//   A byte(R,k)  = (R>>4)*8192 + (k>>5)*1024 + ((k>>3)&3)*256 + (R&15)*16
//   B byte(R,k)  = (R>>7)*65536 + ((R>>4)&7)*8192 + (k>>5)*1024
//                  + ((k>>3)&3)*256 + (R&15)*16
// B row R scaled by 30*rel[R]*log2e BEFORE bf16 quantization; pad rows = 0.
// Iteration is DST-granule-linear: writes perfectly coalesced, reads use
// full 128B lines within each wave.
// ---------------------------------------------------------------------------
__global__ void prep_kernel(const float* __restrict__ inputs,
                            const float* __restrict__ lut,
                            const float* __restrict__ cq,
                            const float* __restrict__ rel,
                            unsigned short* __restrict__ in2,
                            unsigned short* __restrict__ bank3) {
  const int GIN = NROWS * (DDIM / 8);   // 262144 dst granules (16B)
  const int GBK = LPAD * (DDIM / 8);    // 339968 dst granules
  const int total = GIN + GBK;
  for (int d = blockIdx.x * blockDim.x + threadIdx.x; d < total;
       d += gridDim.x * blockDim.x) {
    const float* src = nullptr;
    unsigned short* dst;
    float scale = 1.0f;
    bool zero = false;
    if (d < GIN) {
      // A: rowblk = d>>9, kk = (d>>6)&7, kgrp = (d>>4)&3, r16 = d&15
      const int R = ((d >> 9) << 4) | (d & 15);
      const int c8 = (((d >> 6) & 7) << 2) | ((d >> 4) & 3);
      src = inputs + R * DDIM + c8 * 8;
      dst = in2 + (size_t)d * 8;
    } else {
      const int b = d - GIN;
      // B: t = b>>12, colblk = (b>>9)&7, kk = (b>>6)&7, kgrp=(b>>4)&3, c16=b&15
      const int R = ((b >> 12) << 7) | (((b >> 9) & 7) << 4) | (b & 15);
      const int c8 = (((b >> 6) & 7) << 2) | ((b >> 4) & 3);
      dst = bank3 + (size_t)b * 8;
      if (R < NPIDS) src = lut + (size_t)R * DDIM + c8 * 8;
      else if (R < LCOLS) src = cq + (size_t)(R - NPIDS) * DDIM + c8 * 8;
      else zero = true;
      if (!zero) scale = OIM_SCALE * LOG2E * rel[R];
    }
    ushort8 o = {0, 0, 0, 0, 0, 0, 0, 0};
    if (!zero) {
      const f32x4* s4 = (const f32x4*)src;
      f32x4 v0 = s4[0], v1 = s4[1];
      o[0] = f2bf(v0[0] * scale); o[1] = f2bf(v0[1] * scale);
      o[2] = f2bf(v0[2] * scale); o[3] = f2bf(v0[3] * scale);
      o[4] = f2bf(v1[0] * scale); o[5] = f2bf(v1[1] * scale);
      o[6] = f2bf(v1[2] * scale); o[7] = f2bf(v1[3] * scale);
    }
    *(ushort8*)dst = o;
  }
}

// ---------------------------------------------------------------------------
// main: fused GEMM + sum-of-exp + label-logit capture. NO LDS, NO BARRIERS.
// 256 blocks = 1 block/CU, 4 waves = 1 wave/SIMD (full 512-VGPR budget).
// sp = bid&3: bid%8 = XCD id => each XCD serves ONE sp (B slice 1.3MB) and
// 32 bm values (A slice 2MB) -> whole working set L2-resident.
// Wave tile 64x64 = 4mi x 4ni of 16x16x32. A: 32 frags in registers (128
// VGPR). B: register double-buffer b0/b1 (one ni-block = 8 frags), each frag
// a single coalesced dwordx4 from the frag-order layout. acc double-banked;
// previous ni-block's exp2-epilogue (2 elements/kstep) interleaved into the
// MFMA stream so it issues in the MFMA shadow (in-order wave issue).
// ---------------------------------------------------------------------------
#define LOADF(B, ADDR)                                                    \
  do {                                                                    \
    const char* _a = (ADDR);                                              \
    _Pragma("unroll") for (int _kk = 0; _kk < 8; ++_kk)                   \
        B[_kk] = *(const bf16x8*)(_a + _kk * 1024);                       \
  } while (0)

#define EPIEL(EACC, IDX, PCOLV)                                           \
  do {                                                                    \
    const int _mi2 = (IDX) >> 2, _r2 = (IDX)&3;                           \
    const float _v = EACC[_mi2][_r2];                                     \
    se[_mi2][_r2] += __builtin_amdgcn_exp2f(_v);                          \
    if (lbl[_mi2][_r2] == (PCOLV)) cap[_mi2][_r2] = _v;                   \
  } while (0)

#define SLICE(ACC, BCUR, EACC, PCOLV)                                     \
  do {                                                                    \
    _Pragma("unroll") for (int _kk = 0; _kk < 8; ++_kk) {                 \
      _Pragma("unroll") for (int _mi = 0; _mi < 4; ++_mi)                 \
          ACC[_mi] = __builtin_amdgcn_mfma_f32_16x16x32_bf16(             \
              aR[_mi][_kk], BCUR[_kk], (_kk == 0) ? vzero : ACC[_mi], 0,  \
              0, 0);                                                      \
      EPIEL(EACC, _kk * 2, PCOLV);                                        \
      EPIEL(EACC, _kk * 2 + 1, PCOLV);                                    \
    }                                                                     \
  } while (0)

__global__ __launch_bounds__(256, 1) void oim_main_kernel(
    const unsigned short* __restrict__ in2,
    const unsigned short* __restrict__ bank3,
    const int* __restrict__ label,
    float* __restrict__ parts,
    float* __restrict__ rowlogit) {
  const int tid = threadIdx.x;
  const int lane = tid & 63;
  const int wv = tid >> 6;
  const int wrow = wv >> 1;   // 0..1
  const int wcol = wv & 1;    // 0..1
  const int ql = lane & 15;
  const int h = lane >> 4;    // 0..3

  const int bid = blockIdx.x;
  const int sp = bid & 3;
  const int bm = bid >> 2;
  const int ntiles = (sp < 3) ? 21 : 20;

  // ---- A fragments -> registers (32 coalesced dwordx4) ----
  bf16x8 aR[4][8];
  {
    const char* ab =
        (const char*)in2 + (size_t)(bm * 8 + wrow * 4) * 8192 + lane * 16;
#pragma unroll
    for (int mi = 0; mi < 4; ++mi)
#pragma unroll
      for (int kk = 0; kk < 8; ++kk)
        aR[mi][kk] = *(const bf16x8*)(ab + mi * 8192 + kk * 1024);
  }
  // labels for this lane's 16 output rows
  const int rowb = bm * 128 + wrow * 64 + h * 4;
  int4v lbl[4];
#pragma unroll
  for (int mi = 0; mi < 4; ++mi)
    lbl[mi] = *(const int4v*)(label + rowb + mi * 16);

  const f32x4 vzero = {0.f, 0.f, 0.f, 0.f};
  const f32x4 vneg = {-1e30f, -1e30f, -1e30f, -1e30f};
  f32x4 accA[4], accB[4];
  bf16x8 b0[8], b1[8];
  float se[4][4], cap[4][4];
#pragma unroll
  for (int a = 0; a < 4; ++a) {
    accB[a] = vneg;  // primes first epilogue: exp2(-1e30) = 0
#pragma unroll
    for (int b = 0; b < 4; ++b) { se[a][b] = 0.f; cap[a][b] = -1e30f; }
  }

  // B tile base: frag(ni,kk) at tb + ni*8192 + kk*1024
  const char* tb =
      (const char*)bank3 + (size_t)sp * 65536 + wcol * 32768 + lane * 16;
  int pcol = -1;                              // col of previous slice
  int ct = sp * 128 + wcol * 64 + ql;         // col base of current tile

  LOADF(b0, tb);
  for (int i = 0; i < ntiles; ++i) {
    const char* nt = tb + 262144;             // next tile (t += NSPLIT)
    const char* nx = (i + 1 < ntiles) ? nt : tb;  // harmless dummy on last
    LOADF(b1, tb + 8192);                     // ni=1
    SLICE(accA, b0, accB, pcol);
    pcol = ct;
    LOADF(b0, tb + 16384);                    // ni=2
    SLICE(accB, b1, accA, pcol);
    pcol = ct + 16;
    LOADF(b1, tb + 24576);                    // ni=3
    SLICE(accA, b0, accB, pcol);
    pcol = ct + 32;
    LOADF(b0, nx);                            // next tile ni=0
    SLICE(accB, b1, accA, pcol);
    pcol = ct + 48;
    tb = nt;
    ct += 512;
  }
  // final epilogue (last ni=3 lives in accB)
#pragma unroll
  for (int e = 0; e < 16; ++e) EPIEL(accB, e, pcol);

  // captured label logits (exactly one thread per labeled row matches)
#pragma unroll
  for (int mi = 0; mi < 4; ++mi)
#pragma unroll
    for (int r = 0; r < 4; ++r)
      if (cap[mi][r] > -1e29f) rowlogit[rowb + mi * 16 + r] = cap[mi][r];

  // reduce across the 16 column-lanes (ql) of each row group
#pragma unroll
  for (int mi = 0; mi < 4; ++mi)
#pragma unroll
    for (int r = 0; r < 4; ++r) {
      float v = se[mi][r];
      v += __shfl_xor(v, 1);
      v += __shfl_xor(v, 2);
      v += __shfl_xor(v, 4);
      v += __shfl_xor(v, 8);
      se[mi][r] = v;
    }
  if (ql == 0) {
    const int part = sp * 2 + wcol;  // deterministic partial slot
#pragma unroll
    for (int mi = 0; mi < 4; ++mi) {
      f32x4 o = {se[mi][0], se[mi][1], se[mi][2], se[mi][3]};
      *(f32x4*)(parts + (size_t)part * NROWS + rowb + mi * 16) = o;
    }
  }
}

// ---------------------------------------------------------------------------
// reduce1: 32 blocks x 256 threads, one row per thread.
// tot = sum(parts) - PADCOLS; s = ln2*(log2(tot) - rowlogit) for valid rows.
// ---------------------------------------------------------------------------
__global__ void reduce1_kernel(const float* __restrict__ parts,
                               const float* __restrict__ rowlogit,
                               const int* __restrict__ label,
                               float* __restrict__ blk) {
  const int r = blockIdx.x * 256 + threadIdx.x;
  float s = 0.0f, c = 0.0f;
  if (label[r] != IGNORE_IDX) {
    float tot = 0.0f;
#pragma unroll
    for (int p = 0; p < NPARTS; ++p) tot += parts[p * NROWS + r];
    tot -= (float)PADCOLS;
    s = LN2f * (__builtin_log2f(tot) - rowlogit[r]);
    c = 1.0f;
  }
#pragma unroll
  for (int m = 1; m < 64; m <<= 1) {
    s += __shfl_xor(s, m);
    c += __shfl_xor(c, m);
  }
  __shared__ float ss[4], sc[4];
  const int wv = threadIdx.x >> 6, lane = threadIdx.x & 63;
  if (lane == 0) { ss[wv] = s; sc[wv] = c; }
  __syncthreads();
  if (threadIdx.x == 0) {
    blk[blockIdx.x * 2 + 0] = ss[0] + ss[1] + ss[2] + ss[3];
    blk[blockIdx.x * 2 + 1] = sc[0] + sc[1] + sc[2] + sc[3];
  }
}

__global__ void reduce2_kernel(const float* __restrict__ blk,
                               float* __restrict__ out) {
  const int lane = threadIdx.x;
  float s = (lane < 32) ? blk[lane * 2 + 0] : 0.0f;
  float c = (lane < 32) ? blk[lane * 2 + 1] : 0.0f;
#pragma unroll
  for (int m = 1; m < 32; m <<= 1) {
    s += __shfl_xor(s, m);
    c += __shfl_xor(c, m);
  }
  if (lane == 0) out[0] = s / fmaxf(c, 1.0f);
}

extern "C" void kernel_launch(void* const* d_in, const int* in_sizes, int n_in,
                              void* d_out, int out_size, void* d_ws,
                              size_t ws_size, hipStream_t stream) {
  const float* inputs = (const float*)d_in[0];
  const int* label = (const int*)d_in[1];
  // d_in[2] = ious (unused by the reference loss)
  const float* lut = (const float*)d_in[3];
  const float* cq = (const float*)d_in[4];
  const float* rel = (const float*)d_in[5];
  float* out = (float*)d_out;
  char* ws = (char*)d_ws;
  if (ws_size < WS_NEED) return;

  unsigned short* in2 = (unsigned short*)(ws + WS_INBF);
  unsigned short* bank3 = (unsigned short*)(ws + WS_BANK);
  float* parts = (float*)(ws + WS_PARTS);
  float* rowlogit = (float*)(ws + WS_RLOGIT);
  float* blk = (float*)(ws + WS_BLK);

  prep_kernel<<<dim3(1024), dim3(256), 0, stream>>>(inputs, lut, cq, rel,
                                                    in2, bank3);
  oim_main_kernel<<<dim3(64 * NSPLIT), dim3(256), 0, stream>>>(
      in2, bank3, label, parts, rowlogit);
  reduce1_kernel<<<dim3(32), dim3(256), 0, stream>>>(parts, rowlogit, label,
                                                     blk);
  reduce2_kernel<<<dim3(1), dim3(64), 0, stream>>>(blk, out);
}

// Round 6
// 81.857 us; speedup vs baseline: 1.9560x; 1.9560x over previous
//
#include <hip/hip_runtime.h>
#include <stdint.h>

#define NROWS 8192
#define DDIM 256
#define NPIDS 5532
#define NCQ 5000
#define LCOLS 10532            // NPIDS + NCQ
#define IGNORE_IDX 5554
#define NT 83                  // ceil(10532/128)
#define LPAD (NT * 128)        // 10624
#define NSPLIT 6
#define NPARTS (NSPLIT * 2)    // 12 partial slots per row
#define PADCOLS (LPAD - LCOLS) // 92, each contributes exp2(0)=1 exactly
#define OIM_SCALE 30.0f
#define LOG2E 1.4426950408889634f
#define LN2f 0.6931471805599453f

using f32x4 = __attribute__((ext_vector_type(4))) float;
using bf16x8 = __attribute__((ext_vector_type(8))) __bf16;
using ushort8 = __attribute__((ext_vector_type(8))) unsigned short;
using int4v = __attribute__((ext_vector_type(4))) int;

// ws layout (bytes)
#define WS_INBF 0u             // 8192*256*2   = 4,194,304 (frag-order bf16)
#define WS_BANK 4194304u       // 10624*256*2  = 5,439,488 (frag-order, rse-scaled)
#define WS_PARTS 9633792u      // 12*8192*4    = 393,216
#define WS_RLOGIT 10027008u    // 8192*4       = 32,768
#define WS_BLK 10059776u       // 32*2*4       = 256
#define WS_NEED 10060032u

__device__ __forceinline__ unsigned short f2bf(float f) {
  union { float f; uint32_t u; } v; v.f = f;
  uint32_t u = v.u;
  uint32_t r = (u + 0x7FFFu + ((u >> 16) & 1u)) >> 16;  // RNE
  return (unsigned short)r;
}

__device__ __forceinline__ void async16(const void* g, void* l) {
  __builtin_amdgcn_global_load_lds(
      (const __attribute__((address_space(1))) uint32_t*)g,
      (__attribute__((address_space(3))) uint32_t*)l, 16, 0, 0);
}

// ---------------------------------------------------------------------------
// prep (same as round 5, proven): store A and B in MFMA fragment-consumption
// order so every main-loop operand transfer is ONE coalesced 1KB op:
//   A byte(R,k)  = (R>>4)*8192 + (k>>5)*1024 + ((k>>3)&3)*256 + (R&15)*16
//   B byte(R,k)  = (R>>7)*65536 + ((R>>4)&7)*8192 + (k>>5)*1024
//                  + ((k>>3)&3)*256 + (R&15)*16
// B row R scaled by 30*rel[R]*log2e BEFORE bf16 quantization; pad rows = 0.
// ---------------------------------------------------------------------------
__global__ void prep_kernel(const float* __restrict__ inputs,
                            const float* __restrict__ lut,
                            const float* __restrict__ cq,
                            const float* __restrict__ rel,
                            unsigned short* __restrict__ in2,
                            unsigned short* __restrict__ bank3) {
  const int GIN = NROWS * (DDIM / 8);   // 262144 dst granules (16B)
  const int GBK = LPAD * (DDIM / 8);    // 339968 dst granules
  const int total = GIN + GBK;
  for (int d = blockIdx.x * blockDim.x + threadIdx.x; d < total;
       d += gridDim.x * blockDim.x) {
    const float* src = nullptr;
    unsigned short* dst;
    float scale = 1.0f;
    bool zero = false;
    if (d < GIN) {
      const int R = ((d >> 9) << 4) | (d & 15);
      const int c8 = (((d >> 6) & 7) << 2) | ((d >> 4) & 3);
      src = inputs + R * DDIM + c8 * 8;
      dst = in2 + (size_t)d * 8;
    } else {
      const int b = d - GIN;
      const int R = ((b >> 12) << 7) | (((b >> 9) & 7) << 4) | (b & 15);
      const int c8 = (((b >> 6) & 7) << 2) | ((b >> 4) & 3);
      dst = bank3 + (size_t)b * 8;
      if (R < NPIDS) src = lut + (size_t)R * DDIM + c8 * 8;
      else if (R < LCOLS) src = cq + (size_t)(R - NPIDS) * DDIM + c8 * 8;
      else zero = true;
      if (!zero) scale = OIM_SCALE * LOG2E * rel[R];
    }
    ushort8 o = {0, 0, 0, 0, 0, 0, 0, 0};
    if (!zero) {
      const f32x4* s4 = (const f32x4*)src;
      f32x4 v0 = s4[0], v1 = s4[1];
      o[0] = f2bf(v0[0] * scale); o[1] = f2bf(v0[1] * scale);
      o[2] = f2bf(v0[2] * scale); o[3] = f2bf(v0[3] * scale);
      o[4] = f2bf(v1[0] * scale); o[5] = f2bf(v1[1] * scale);
      o[6] = f2bf(v1[2] * scale); o[7] = f2bf(v1[3] * scale);
    }
    *(ushort8*)dst = o;
  }
}

// ---------------------------------------------------------------------------
// main: fused GEMM + sum-of-exp + label-logit capture. ZERO BARRIERS.
// 768 blocks = 3/CU, 256 threads = 4 waves, each wave fully independent:
// wave tile 32x64 (2mi x 4ni of 16x16x32), block tile 64x128.
// A: 64-VGPR register fragments (loaded once, pre-loop).
// B: WAVE-PRIVATE 3-buffer LDS ring (3 x 4KB), depth-2 prefetch via
//    global_load_lds; per-wave counted `s_waitcnt vmcnt(4)` (vmcnt is
//    per-wave; wave issue is in-order -> exact accounting, no s_barrier).
// B rows pre-scaled by rse -> tile epilogue = exp2(acc)+add (+label capture).
// Waves de-synchronize naturally: one wave's epilogue hides under the other
// two waves' MFMA streams on the same SIMD (3 waves/SIMD).
// ---------------------------------------------------------------------------
__global__ __launch_bounds__(256, 3) void oim_main_kernel(
    const unsigned short* __restrict__ in2,
    const unsigned short* __restrict__ bank3,
    const int* __restrict__ label,
    float* __restrict__ parts,
    float* __restrict__ rowlogit) {
  __shared__ char ring_all[49152];  // 4 waves x 3 x 4KB
  const int tid = threadIdx.x;
  const int lane = tid & 63;
  const int wv = tid >> 6;
  const int wrow = wv >> 1;   // 0..1
  const int wcol = wv & 1;    // 0..1
  const int ql = lane & 15;
  const int h = lane >> 4;    // 0..3

  const int bid = blockIdx.x;
  const int sp = bid % NSPLIT;
  const int bm = bid / NSPLIT;          // 0..127 (64-row block)
  const int ntiles = (sp < 5) ? 14 : 13;

  char* ring = ring_all + wv * 12288;   // wave-private 12KB

  // ---- A fragments -> registers (16 coalesced dwordx4, pre-loop) ----
  bf16x8 aR[2][8];
  {
    const char* ab =
        (const char*)in2 + (size_t)(bm * 4 + wrow * 2) * 8192 + lane * 16;
#pragma unroll
    for (int mi = 0; mi < 2; ++mi)
#pragma unroll
      for (int kk = 0; kk < 8; ++kk)
        aR[mi][kk] = *(const bf16x8*)(ab + mi * 8192 + kk * 1024);
  }
  const int rowb = bm * 64 + wrow * 32 + h * 4;
  int4v lbl[2];
#pragma unroll
  for (int mi = 0; mi < 2; ++mi)
    lbl[mi] = *(const int4v*)(label + rowb + mi * 16);

  // wave's B source: tile base + its 64-col half (4 colblks of 8KB)
  const char* cb = (const char*)bank3 + (size_t)sp * 65536 + wcol * 32768;
  const char* sg = cb + lane * 16;          // per-lane global src
  const size_t tstep = (size_t)NSPLIT * 65536;

  // prologue: stage kk=0 -> buf0, kk=1 -> buf1 (8 ops in flight)
#pragma unroll
  for (int j = 0; j < 4; ++j) async16(sg + j * 8192, ring + j * 1024);
#pragma unroll
  for (int j = 0; j < 4; ++j)
    async16(sg + j * 8192 + 1024, ring + 4096 + j * 1024);

  const f32x4 vzero = {0.f, 0.f, 0.f, 0.f};
  f32x4 acc[2][4];
  float se[2][4], cap[2][4];
#pragma unroll
  for (int a = 0; a < 2; ++a)
#pragma unroll
    for (int b = 0; b < 4; ++b) { se[a][b] = 0.f; cap[a][b] = -1e30f; }

  int ro = 0;                               // read-buffer byte offset
  int tcol = sp * 128 + wcol * 64 + ql;     // col base of current tile

  for (int i = 0; i < ntiles; ++i) {
    const bool more = (i + 1 < ntiles);
    const char* nsg = sg + tstep;           // next tile per-lane src
#pragma unroll
    for (int q = 0; q < 8; ++q) {
      // wait current buffer (stage(Q) done; stage(Q+1) may stay in flight)
      if (q == 7 && !more)
        asm volatile("s_waitcnt vmcnt(0)" ::: "memory");
      else
        asm volatile("s_waitcnt vmcnt(4)" ::: "memory");
      // stage phase Q+2 into buffer (ro+8192)%12288
      int so = ro + 8192; if (so >= 12288) so -= 12288;
      if (q < 6) {                          // current tile, kk = q+2
#pragma unroll
        for (int j = 0; j < 4; ++j)
          async16(sg + j * 8192 + (q + 2) * 1024, ring + so + j * 1024);
      } else if (more) {                    // next tile, kk = q-6
#pragma unroll
        for (int j = 0; j < 4; ++j)
          async16(nsg + j * 8192 + (q - 6) * 1024, ring + so + j * 1024);
      }
      // ds_read 4 B-frags (conflict-free: lane*16 linear) + 16 MFMA
      bf16x8 bF[4];
      const char* rp = ring + ro + lane * 16;
#pragma unroll
      for (int ni = 0; ni < 4; ++ni)
        bF[ni] = *(const bf16x8*)(rp + ni * 1024);
      __builtin_amdgcn_s_setprio(1);
#pragma unroll
      for (int mi = 0; mi < 2; ++mi)
#pragma unroll
        for (int ni = 0; ni < 4; ++ni)
          acc[mi][ni] = __builtin_amdgcn_mfma_f32_16x16x32_bf16(
              aR[mi][q], bF[ni], (q == 0) ? vzero : acc[mi][ni], 0, 0, 0);
      __builtin_amdgcn_s_setprio(0);
      ro += 4096; if (ro == 12288) ro = 0;
    }
    // tile epilogue: exp2 accumulate + label-logit capture (log2 units)
#pragma unroll
    for (int ni = 0; ni < 4; ++ni) {
      const int col = tcol + ni * 16;
#pragma unroll
      for (int mi = 0; mi < 2; ++mi)
#pragma unroll
        for (int r = 0; r < 4; ++r) {
          const float v = acc[mi][ni][r];
          se[mi][r] += __builtin_amdgcn_exp2f(v);
          if (lbl[mi][r] == col) cap[mi][r] = v;
        }
    }
    tcol += NSPLIT * 128;
    sg = nsg;
  }

  // captured label logits (exactly one thread per labeled row matches)
#pragma unroll
  for (int mi = 0; mi < 2; ++mi)
#pragma unroll
    for (int r = 0; r < 4; ++r)
      if (cap[mi][r] > -1e29f) rowlogit[rowb + mi * 16 + r] = cap[mi][r];

  // reduce across the 16 column-lanes (ql) of each row group
#pragma unroll
  for (int mi = 0; mi < 2; ++mi)
#pragma unroll
    for (int r = 0; r < 4; ++r) {
      float v = se[mi][r];
      v += __shfl_xor(v, 1);
      v += __shfl_xor(v, 2);
      v += __shfl_xor(v, 4);
      v += __shfl_xor(v, 8);
      se[mi][r] = v;
    }
  if (ql == 0) {
    const int part = sp * 2 + wcol;  // deterministic partial slot, 0..11
#pragma unroll
    for (int mi = 0; mi < 2; ++mi) {
      f32x4 o = {se[mi][0], se[mi][1], se[mi][2], se[mi][3]};
      *(f32x4*)(parts + (size_t)part * NROWS + rowb + mi * 16) = o;
    }
  }
}

// ---------------------------------------------------------------------------
// reduce1: 32 blocks x 256 threads, one row per thread.
// tot = sum(parts) - PADCOLS; s = ln2*(log2(tot) - rowlogit) for valid rows.
// ---------------------------------------------------------------------------
__global__ void reduce1_kernel(const float* __restrict__ parts,
                               const float* __restrict__ rowlogit,
                               const int* __restrict__ label,
                               float* __restrict__ blk) {
  const int r = blockIdx.x * 256 + threadIdx.x;
  float s = 0.0f, c = 0.0f;
  if (label[r] != IGNORE_IDX) {
    float tot = 0.0f;
#pragma unroll
    for (int p = 0; p < NPARTS; ++p) tot += parts[p * NROWS + r];
    tot -= (float)PADCOLS;
    s = LN2f * (__builtin_log2f(tot) - rowlogit[r]);
    c = 1.0f;
  }
#pragma unroll
  for (int m = 1; m < 64; m <<= 1) {
    s += __shfl_xor(s, m);
    c += __shfl_xor(c, m);
  }
  __shared__ float ss[4], sc[4];
  const int wv = threadIdx.x >> 6, lane = threadIdx.x & 63;
  if (lane == 0) { ss[wv] = s; sc[wv] = c; }
  __syncthreads();
  if (threadIdx.x == 0) {
    blk[blockIdx.x * 2 + 0] = ss[0] + ss[1] + ss[2] + ss[3];
    blk[blockIdx.x * 2 + 1] = sc[0] + sc[1] + sc[2] + sc[3];
  }
}

__global__ void reduce2_kernel(const float* __restrict__ blk,
                               float* __restrict__ out) {
  const int lane = threadIdx.x;
  float s = (lane < 32) ? blk[lane * 2 + 0] : 0.0f;
  float c = (lane < 32) ? blk[lane * 2 + 1] : 0.0f;
#pragma unroll
  for (int m = 1; m < 32; m <<= 1) {
    s += __shfl_xor(s, m);
    c += __shfl_xor(c, m);
  }
  if (lane == 0) out[0] = s / fmaxf(c, 1.0f);
}

extern "C" void kernel_launch(void* const* d_in, const int* in_sizes, int n_in,
                              void* d_out, int out_size, void* d_ws,
                              size_t ws_size, hipStream_t stream) {
  const float* inputs = (const float*)d_in[0];
  const int* label = (const int*)d_in[1];
  // d_in[2] = ious (unused by the reference loss)
  const float* lut = (const float*)d_in[3];
  const float* cq = (const float*)d_in[4];
  const float* rel = (const float*)d_in[5];
  float* out = (float*)d_out;
  char* ws = (char*)d_ws;
  if (ws_size < WS_NEED) return;

  unsigned short* in2 = (unsigned short*)(ws + WS_INBF);
  unsigned short* bank3 = (unsigned short*)(ws + WS_BANK);
  float* parts = (float*)(ws + WS_PARTS);
  float* rowlogit = (float*)(ws + WS_RLOGIT);
  float* blk = (float*)(ws + WS_BLK);

  prep_kernel<<<dim3(1024), dim3(256), 0, stream>>>(inputs, lut, cq, rel,
                                                    in2, bank3);
  oim_main_kernel<<<dim3(128 * NSPLIT), dim3(256), 0, stream>>>(
      in2, bank3, label, parts, rowlogit);
  reduce1_kernel<<<dim3(32), dim3(256), 0, stream>>>(parts, rowlogit, label,
                                                     blk);
  reduce2_kernel<<<dim3(1), dim3(64), 0, stream>>>(blk, out);
}

// Round 7
// 78.908 us; speedup vs baseline: 2.0291x; 1.0374x over previous
//
#include <hip/hip_runtime.h>
#include <stdint.h>

#define NROWS 8192
#define DDIM 256
#define NPIDS 5532
#define NCQ 5000
#define LCOLS 10532            // NPIDS + NCQ
#define IGNORE_IDX 5554
#define NT 83                  // ceil(10532/128)
#define LPAD (NT * 128)        // 10624
#define NSPLIT 6
#define NPARTS (NSPLIT * 2)    // 12 partial slots per row
#define PADCOLS (LPAD - LCOLS) // 92, each contributes exp2(0)=1 exactly
#define OIM_SCALE 30.0f
#define LOG2E 1.4426950408889634f
#define LN2f 0.6931471805599453f

using f32x4 = __attribute__((ext_vector_type(4))) float;
using bf16x8 = __attribute__((ext_vector_type(8))) __bf16;
using ushort8 = __attribute__((ext_vector_type(8))) unsigned short;
using int4v = __attribute__((ext_vector_type(4))) int;

// ws layout (bytes)
#define WS_INBF 0u             // 8192*256*2   = 4,194,304 (frag-order bf16)
#define WS_BANK 4194304u       // 10624*256*2  = 5,439,488 (frag-order, rse-scaled)
#define WS_PARTS 9633792u      // 12*8192*4    = 393,216
#define WS_RLOGIT 10027008u    // 8192*4       = 32,768
#define WS_BLK 10059776u       // 32*2*4       = 256
#define WS_NEED 10060032u

__device__ __forceinline__ unsigned short f2bf(float f) {
  union { float f; uint32_t u; } v; v.f = f;
  uint32_t u = v.u;
  uint32_t r = (u + 0x7FFFu + ((u >> 16) & 1u)) >> 16;  // RNE
  return (unsigned short)r;
}

__device__ __forceinline__ void async16(const void* g, void* l) {
  __builtin_amdgcn_global_load_lds(
      (const __attribute__((address_space(1))) uint32_t*)g,
      (__attribute__((address_space(3))) uint32_t*)l, 16, 0, 0);
}

// ---------------------------------------------------------------------------
// prep (unchanged, proven): store A and B in MFMA fragment-consumption order
// so every main-loop operand transfer is ONE coalesced 1KB op:
//   A byte(R,k)  = (R>>4)*8192 + (k>>5)*1024 + ((k>>3)&3)*256 + (R&15)*16
//   B byte(R,k)  = (R>>7)*65536 + ((R>>4)&7)*8192 + (k>>5)*1024
//                  + ((k>>3)&3)*256 + (R&15)*16
// B row R scaled by 30*rel[R]*log2e BEFORE bf16 quantization; pad rows = 0.
// ---------------------------------------------------------------------------
__global__ void prep_kernel(const float* __restrict__ inputs,
                            const float* __restrict__ lut,
                            const float* __restrict__ cq,
                            const float* __restrict__ rel,
                            unsigned short* __restrict__ in2,
                            unsigned short* __restrict__ bank3) {
  const int GIN = NROWS * (DDIM / 8);   // 262144 dst granules (16B)
  const int GBK = LPAD * (DDIM / 8);    // 339968 dst granules
  const int total = GIN + GBK;
  for (int d = blockIdx.x * blockDim.x + threadIdx.x; d < total;
       d += gridDim.x * blockDim.x) {
    const float* src = nullptr;
    unsigned short* dst;
    float scale = 1.0f;
    bool zero = false;
    if (d < GIN) {
      const int R = ((d >> 9) << 4) | (d & 15);
      const int c8 = (((d >> 6) & 7) << 2) | ((d >> 4) & 3);
      src = inputs + R * DDIM + c8 * 8;
      dst = in2 + (size_t)d * 8;
    } else {
      const int b = d - GIN;
      const int R = ((b >> 12) << 7) | (((b >> 9) & 7) << 4) | (b & 15);
      const int c8 = (((b >> 6) & 7) << 2) | ((b >> 4) & 3);
      dst = bank3 + (size_t)b * 8;
      if (R < NPIDS) src = lut + (size_t)R * DDIM + c8 * 8;
      else if (R < LCOLS) src = cq + (size_t)(R - NPIDS) * DDIM + c8 * 8;
      else zero = true;
      if (!zero) scale = OIM_SCALE * LOG2E * rel[R];
    }
    ushort8 o = {0, 0, 0, 0, 0, 0, 0, 0};
    if (!zero) {
      const f32x4* s4 = (const f32x4*)src;
      f32x4 v0 = s4[0], v1 = s4[1];
      o[0] = f2bf(v0[0] * scale); o[1] = f2bf(v0[1] * scale);
      o[2] = f2bf(v0[2] * scale); o[3] = f2bf(v0[3] * scale);
      o[4] = f2bf(v1[0] * scale); o[5] = f2bf(v1[1] * scale);
      o[6] = f2bf(v1[2] * scale); o[7] = f2bf(v1[3] * scale);
    }
    *(ushort8*)dst = o;
  }
}

// ---------------------------------------------------------------------------
// main: fused GEMM + sum-of-exp + label-logit capture. ZERO BARRIERS.
// 768 blocks = 3/CU, 256 threads = 4 independent waves, wave tile 32x64.
// XCD-ALIGNED 2D decode (xcd = bid&7, round-robin dispatch): A-group =
// xcd>>1 (32 bm = 1.05MB), sp-group = xcd&1 (3 slices = 2.72MB) -> per-XCD
// working set 3.8MB <= 4MB L2; all 96 blocks of an XCD run concurrently ->
// stage loads are L2 hits (~200-300cy) < depth-2 lookahead (~310-600cy).
// B: wave-private 3 x 4KB LDS ring, STAGE-FIRST then counted
// `s_waitcnt vmcnt(8)` (stage issue sits inside the stall shadow; vmcnt
// retires in order; pre-loop A/label loads are strictly older => safe).
// ---------------------------------------------------------------------------
__global__ __launch_bounds__(256, 3) void oim_main_kernel(
    const unsigned short* __restrict__ in2,
    const unsigned short* __restrict__ bank3,
    const int* __restrict__ label,
    float* __restrict__ parts,
    float* __restrict__ rowlogit) {
  __shared__ __attribute__((aligned(16))) char ring_all[49152];
  const int tid = threadIdx.x;
  const int lane = tid & 63;
  const int wv = tid >> 6;
  const int wrow = wv >> 1;   // 0..1
  const int wcol = wv & 1;    // 0..1
  const int ql = lane & 15;
  const int h = lane >> 4;    // 0..3

  const int bid = blockIdx.x;
  const int xcd = bid & 7;
  const int r0 = bid >> 3;                    // 0..95
  const int bm = (xcd >> 1) * 32 + (r0 & 31); // 0..127
  const int sp = (xcd & 1) * 3 + (r0 >> 5);   // 0..5
  const int ntiles = (sp < 5) ? 14 : 13;
  const int NQ = ntiles * 8;

  char* ring = ring_all + wv * 12288;   // wave-private 12KB

  // ---- A fragments -> registers (16 coalesced dwordx4, pre-loop) ----
  bf16x8 aR[2][8];
  {
    const char* ab =
        (const char*)in2 + (size_t)(bm * 4 + wrow * 2) * 8192 + lane * 16;
#pragma unroll
    for (int mi = 0; mi < 2; ++mi)
#pragma unroll
      for (int kk = 0; kk < 8; ++kk)
        aR[mi][kk] = *(const bf16x8*)(ab + mi * 8192 + kk * 1024);
  }
  const int rowb = bm * 64 + wrow * 32 + h * 4;
  int4v lbl[2];
#pragma unroll
  for (int mi = 0; mi < 2; ++mi)
    lbl[mi] = *(const int4v*)(label + rowb + mi * 16);

  // wave's B source: tile base + its 64-col half (4 colblks of 8KB)
  const char* cb = (const char*)bank3 + (size_t)sp * 65536 + wcol * 32768;
  const char* sg = cb + lane * 16;          // per-lane global src
  const size_t tstep = (size_t)NSPLIT * 65536;

  // prologue: stage kk=0 -> buf0, kk=1 -> buf1 (8 ops in flight)
#pragma unroll
  for (int j = 0; j < 4; ++j) async16(sg + j * 8192, ring + j * 1024);
#pragma unroll
  for (int j = 0; j < 4; ++j)
    async16(sg + j * 8192 + 1024, ring + 4096 + j * 1024);

  const f32x4 vzero = {0.f, 0.f, 0.f, 0.f};
  f32x4 acc[2][4];
  float se[2][4], cap[2][4];
#pragma unroll
  for (int a = 0; a < 2; ++a)
#pragma unroll
    for (int b = 0; b < 4; ++b) { se[a][b] = 0.f; cap[a][b] = -1e30f; }

  int ro = 0;                               // read-buffer byte offset
  int tcol = sp * 128 + wcol * 64 + ql;     // col base of current tile

  for (int i = 0; i < ntiles; ++i) {
    const bool more = (i + 1 < ntiles);
    const char* nsg = sg + tstep;           // next tile per-lane src
#pragma unroll
    for (int q = 0; q < 8; ++q) {
      const int Q = i * 8 + q;
      const int ahead = NQ - 1 - Q;
      // STAGE FIRST: phase Q+2 into buffer (ro+8192)%12288
      int so = ro + 8192; if (so >= 12288) so -= 12288;
      if (q < 6) {                          // current tile, kk = q+2
#pragma unroll
        for (int j = 0; j < 4; ++j)
          async16(sg + j * 8192 + (q + 2) * 1024, ring + so + j * 1024);
      } else if (more) {                    // next tile, kk = q-6
#pragma unroll
        for (int j = 0; j < 4; ++j)
          async16(nsg + j * 8192 + (q - 6) * 1024, ring + so + j * 1024);
      }
      // THEN wait for stage(Q): newest 8 ops are stages Q+1,Q+2
      if (ahead >= 2)      asm volatile("s_waitcnt vmcnt(8)" ::: "memory");
      else if (ahead == 1) asm volatile("s_waitcnt vmcnt(4)" ::: "memory");
      else                 asm volatile("s_waitcnt vmcnt(0)" ::: "memory");
      // ds_read 4 B-frags (conflict-free: lane*16 linear) + 8 MFMA
      bf16x8 bF[4];
      const char* rp = ring + ro + lane * 16;
#pragma unroll
      for (int ni = 0; ni < 4; ++ni)
        bF[ni] = *(const bf16x8*)(rp + ni * 1024);
      __builtin_amdgcn_s_setprio(1);
#pragma unroll
      for (int mi = 0; mi < 2; ++mi)
#pragma unroll
        for (int ni = 0; ni < 4; ++ni)
          acc[mi][ni] = __builtin_amdgcn_mfma_f32_16x16x32_bf16(
              aR[mi][q], bF[ni], (q == 0) ? vzero : acc[mi][ni], 0, 0, 0);
      __builtin_amdgcn_s_setprio(0);
      ro += 4096; if (ro == 12288) ro = 0;
    }
    // tile epilogue: exp2 accumulate + label-logit capture (log2 units)
#pragma unroll
    for (int ni = 0; ni < 4; ++ni) {
      const int col = tcol + ni * 16;
#pragma unroll
      for (int mi = 0; mi < 2; ++mi)
#pragma unroll
        for (int r = 0; r < 4; ++r) {
          const float v = acc[mi][ni][r];
          se[mi][r] += __builtin_amdgcn_exp2f(v);
          if (lbl[mi][r] == col) cap[mi][r] = v;
        }
    }
    tcol += NSPLIT * 128;
    sg = nsg;
  }

  // captured label logits (exactly one thread per labeled row matches)
#pragma unroll
  for (int mi = 0; mi < 2; ++mi)
#pragma unroll
    for (int r = 0; r < 4; ++r)
      if (cap[mi][r] > -1e29f) rowlogit[rowb + mi * 16 + r] = cap[mi][r];

  // reduce across the 16 column-lanes (ql) of each row group
#pragma unroll
  for (int mi = 0; mi < 2; ++mi)
#pragma unroll
    for (int r = 0; r < 4; ++r) {
      float v = se[mi][r];
      v += __shfl_xor(v, 1);
      v += __shfl_xor(v, 2);
      v += __shfl_xor(v, 4);
      v += __shfl_xor(v, 8);
      se[mi][r] = v;
    }
  if (ql == 0) {
    const int part = sp * 2 + wcol;  // deterministic partial slot, 0..11
#pragma unroll
    for (int mi = 0; mi < 2; ++mi) {
      f32x4 o = {se[mi][0], se[mi][1], se[mi][2], se[mi][3]};
      *(f32x4*)(parts + (size_t)part * NROWS + rowb + mi * 16) = o;
    }
  }
}

// ---------------------------------------------------------------------------
// reduce1: 32 blocks x 256 threads, one row per thread.
// tot = sum(parts) - PADCOLS; s = ln2*(log2(tot) - rowlogit) for valid rows.
// ---------------------------------------------------------------------------
__global__ void reduce1_kernel(const float* __restrict__ parts,
                               const float* __restrict__ rowlogit,
                               const int* __restrict__ label,
                               float* __restrict__ blk) {
  const int r = blockIdx.x * 256 + threadIdx.x;
  float s = 0.0f, c = 0.0f;
  if (label[r] != IGNORE_IDX) {
    float tot = 0.0f;
#pragma unroll
    for (int p = 0; p < NPARTS; ++p) tot += parts[p * NROWS + r];
    tot -= (float)PADCOLS;
    s = LN2f * (__builtin_log2f(tot) - rowlogit[r]);
    c = 1.0f;
  }
#pragma unroll
  for (int m = 1; m < 64; m <<= 1) {
    s += __shfl_xor(s, m);
    c += __shfl_xor(c, m);
  }
  __shared__ float ss[4], sc[4];
  const int wv = threadIdx.x >> 6, lane = threadIdx.x & 63;
  if (lane == 0) { ss[wv] = s; sc[wv] = c; }
  __syncthreads();
  if (threadIdx.x == 0) {
    blk[blockIdx.x * 2 + 0] = ss[0] + ss[1] + ss[2] + ss[3];
    blk[blockIdx.x * 2 + 1] = sc[0] + sc[1] + sc[2] + sc[3];
  }
}

__global__ void reduce2_kernel(const float* __restrict__ blk,
                               float* __restrict__ out) {
  const int lane = threadIdx.x;
  float s = (lane < 32) ? blk[lane * 2 + 0] : 0.0f;
  float c = (lane < 32) ? blk[lane * 2 + 1] : 0.0f;
#pragma unroll
  for (int m = 1; m < 32; m <<= 1) {
    s += __shfl_xor(s, m);
    c += __shfl_xor(c, m);
  }
  if (lane == 0) out[0] = s / fmaxf(c, 1.0f);
}

extern "C" void kernel_launch(void* const* d_in, const int* in_sizes, int n_in,
                              void* d_out, int out_size, void* d_ws,
                              size_t ws_size, hipStream_t stream) {
  const float* inputs = (const float*)d_in[0];
  const int* label = (const int*)d_in[1];
  // d_in[2] = ious (unused by the reference loss)
  const float* lut = (const float*)d_in[3];
  const float* cq = (const float*)d_in[4];
  const float* rel = (const float*)d_in[5];
  float* out = (float*)d_out;
  char* ws = (char*)d_ws;
  if (ws_size < WS_NEED) return;

  unsigned short* in2 = (unsigned short*)(ws + WS_INBF);
  unsigned short* bank3 = (unsigned short*)(ws + WS_BANK);
  float* parts = (float*)(ws + WS_PARTS);
  float* rowlogit = (float*)(ws + WS_RLOGIT);
  float* blk = (float*)(ws + WS_BLK);

  prep_kernel<<<dim3(1024), dim3(256), 0, stream>>>(inputs, lut, cq, rel,
                                                    in2, bank3);
  oim_main_kernel<<<dim3(128 * NSPLIT), dim3(256), 0, stream>>>(
      in2, bank3, label, parts, rowlogit);
  reduce1_kernel<<<dim3(32), dim3(256), 0, stream>>>(parts, rowlogit, label,
                                                     blk);
  reduce2_kernel<<<dim3(1), dim3(64), 0, stream>>>(blk, out);
}

// Round 8
// 67.171 us; speedup vs baseline: 2.3837x; 1.1747x over previous
//
#include <hip/hip_runtime.h>
#include <stdint.h>

#define NROWS 8192
#define DDIM 256
#define NPIDS 5532
#define NCQ 5000
#define LCOLS 10532            // NPIDS + NCQ
#define IGNORE_IDX 5554
#define NT 83                  // ceil(10532/128)
#define LPAD (NT * 128)        // 10624
#define NSPLIT 4
#define NPARTS (NSPLIT * 2)    // 8 partial slots per row
#define PADCOLS (LPAD - LCOLS) // 92, each contributes exp2(0)=1 exactly
#define TSTEP (NSPLIT * 65536) // 262144 B between consecutive tiles of a split
#define OIM_SCALE 30.0f
#define LOG2E 1.4426950408889634f
#define LN2f 0.6931471805599453f

using f32x4 = __attribute__((ext_vector_type(4))) float;
using bf16x8 = __attribute__((ext_vector_type(8))) __bf16;
using ushort8 = __attribute__((ext_vector_type(8))) unsigned short;
using int4v = __attribute__((ext_vector_type(4))) int;

// ws layout (bytes)
#define WS_INBF 0u             // 8192*256*2   = 4,194,304 (frag-order bf16)
#define WS_BANK 4194304u       // 10624*256*2  = 5,439,488 (frag-order, rse-scaled)
#define WS_PARTS 9633792u      // 8*8192*4     = 262,144
#define WS_RLOGIT 9895936u     // 8192*4       = 32,768
#define WS_BLK 9928704u        // 32*2*4       = 256
#define WS_NEED 9928960u

__device__ __forceinline__ unsigned short f2bf(float f) {
  union { float f; uint32_t u; } v; v.f = f;
  uint32_t u = v.u;
  uint32_t r = (u + 0x7FFFu + ((u >> 16) & 1u)) >> 16;  // RNE
  return (unsigned short)r;
}

__device__ __forceinline__ void async16(const void* g, void* l) {
  __builtin_amdgcn_global_load_lds(
      (const __attribute__((address_space(1))) uint32_t*)g,
      (__attribute__((address_space(3))) uint32_t*)l, 16, 0, 0);
}

// ---------------------------------------------------------------------------
// prep (unchanged, proven): store A and B in MFMA fragment-consumption order
// so every main-loop operand transfer is ONE coalesced 1KB op:
//   A byte(R,k)  = (R>>4)*8192 + (k>>5)*1024 + ((k>>3)&3)*256 + (R&15)*16
//   B byte(R,k)  = (R>>7)*65536 + ((R>>4)&7)*8192 + (k>>5)*1024
//                  + ((k>>3)&3)*256 + (R&15)*16
// B row R scaled by 30*rel[R]*log2e BEFORE bf16 quantization; pad rows = 0.
// ---------------------------------------------------------------------------
__global__ void prep_kernel(const float* __restrict__ inputs,
                            const float* __restrict__ lut,
                            const float* __restrict__ cq,
                            const float* __restrict__ rel,
                            unsigned short* __restrict__ in2,
                            unsigned short* __restrict__ bank3) {
  const int GIN = NROWS * (DDIM / 8);   // 262144 dst granules (16B)
  const int GBK = LPAD * (DDIM / 8);    // 339968 dst granules
  const int total = GIN + GBK;
  for (int d = blockIdx.x * blockDim.x + threadIdx.x; d < total;
       d += gridDim.x * blockDim.x) {
    const float* src = nullptr;
    unsigned short* dst;
    float scale = 1.0f;
    bool zero = false;
    if (d < GIN) {
      const int R = ((d >> 9) << 4) | (d & 15);
      const int c8 = (((d >> 6) & 7) << 2) | ((d >> 4) & 3);
      src = inputs + R * DDIM + c8 * 8;
      dst = in2 + (size_t)d * 8;
    } else {
      const int b = d - GIN;
      const int R = ((b >> 12) << 7) | (((b >> 9) & 7) << 4) | (b & 15);
      const int c8 = (((b >> 6) & 7) << 2) | ((b >> 4) & 3);
      dst = bank3 + (size_t)b * 8;
      if (R < NPIDS) src = lut + (size_t)R * DDIM + c8 * 8;
      else if (R < LCOLS) src = cq + (size_t)(R - NPIDS) * DDIM + c8 * 8;
      else zero = true;
      if (!zero) scale = OIM_SCALE * LOG2E * rel[R];
    }
    ushort8 o = {0, 0, 0, 0, 0, 0, 0, 0};
    if (!zero) {
      const f32x4* s4 = (const f32x4*)src;
      f32x4 v0 = s4[0], v1 = s4[1];
      o[0] = f2bf(v0[0] * scale); o[1] = f2bf(v0[1] * scale);
      o[2] = f2bf(v0[2] * scale); o[3] = f2bf(v0[3] * scale);
      o[4] = f2bf(v1[0] * scale); o[5] = f2bf(v1[1] * scale);
      o[6] = f2bf(v1[2] * scale); o[7] = f2bf(v1[3] * scale);
    }
    *(ushort8*)dst = o;
  }
}

// ---------------------------------------------------------------------------
// main: fused GEMM + sum-of-exp + label-logit capture. ZERO BARRIERS,
// WITHIN-WAVE SOFTWARE PIPELINE (m201-style consume-prev-phase fragments).
// 256 blocks = 1/CU, 4 independent waves = 1 wave/SIMD, full VGPR budget.
// Wave tile 64x64 (4mi x 4ni of 16x16x32); A: 128-VGPR persistent frags.
// B: wave-private 3 x 8KB LDS ring. Per K-quarter Q:
//   stage(Q+2) [8 async16] -> vmcnt(8) [stage(Q+1) landed]
//   -> ds_read frags(Q+1) into the idle reg bank [8 x b128]
//   -> lgkmcnt(8)+sched_barrier [frags(Q), read LAST quarter, resident]
//   -> 32 MFMA on frags(Q), prev-tile exp2 epilogue interleaved 1-per-2-MFMA
// The ds latency of frags(Q+1) hides under the 620-cyc MFMA cluster of Q.
// XCD-aligned decode: per-XCD set = A 1MB + B 2.72MB, L2-resident.
// ---------------------------------------------------------------------------
#define STAGE8(SRC, DSTOFF)                                               \
  do {                                                                    \
    const char* _s = (SRC);                                               \
    char* _d = ringW + (DSTOFF);                                          \
    _Pragma("unroll") for (int _j = 0; _j < 8; ++_j)                      \
      async16(_s + (_j >> 1) * 8192 + (_j & 1) * 1024, _d + _j * 1024);   \
  } while (0)

#define DSREAD8(BANK, ROFF)                                               \
  do {                                                                    \
    const char* _p = vb + (ROFF);                                         \
    _Pragma("unroll") for (int _f = 0; _f < 8; ++_f)                      \
      BANK[_f] =                                                          \
          *(const bf16x8*)(_p + (_f >> 1) * 2048 + (_f & 1) * 1024);      \
  } while (0)

#define EPI1(MI, NI, R, EC)                                               \
  do {                                                                    \
    const float _v = eacc[MI][NI][R];                                     \
    se[MI][R] += __builtin_amdgcn_exp2f(_v);                              \
    if (lbl[MI][R] == (EC)) cap[MI][R] = _v;                              \
  } while (0)

#define CLUSTER(Qq, BC)                                                   \
  do {                                                                    \
    const int _ec = pcol + (Qq) * 16;                                     \
    _Pragma("unroll") for (int _kk = 0; _kk < 2; ++_kk)                   \
      _Pragma("unroll") for (int _mi = 0; _mi < 4; ++_mi) {               \
        _Pragma("unroll") for (int _ni = 0; _ni < 4; ++_ni)               \
          acc[_mi][_ni] = __builtin_amdgcn_mfma_f32_16x16x32_bf16(        \
              aR[_mi][(Qq) * 2 + _kk], BC[_ni * 2 + _kk],                 \
              ((Qq) == 0 && _kk == 0) ? vzero : acc[_mi][_ni], 0, 0, 0);  \
        EPI1(_mi, (Qq), _kk * 2, _ec);                                    \
        EPI1(_mi, (Qq), _kk * 2 + 1, _ec);                                \
      }                                                                   \
  } while (0)

#define QSTEP(Qq, BC, BN)                                                 \
  do {                                                                    \
    STAGE8(sgS, roS);                                                     \
    sgS += ((Qq) == 1) ? (TSTEP - 6144) : 2048;                           \
    roS += 8192; if (roS >= 24576) roS -= 24576;                          \
    asm volatile("s_waitcnt vmcnt(8)" ::: "memory");                      \
    DSREAD8(BN, roN);                                                     \
    roN += 8192; if (roN >= 24576) roN -= 24576;                          \
    asm volatile("s_waitcnt lgkmcnt(8)" ::: "memory");                    \
    __builtin_amdgcn_sched_barrier(0);                                    \
    CLUSTER(Qq, BC);                                                      \
  } while (0)

__global__ __launch_bounds__(256, 1) void oim_main_kernel(
    const unsigned short* __restrict__ in2,
    const unsigned short* __restrict__ bank3,
    const int* __restrict__ label,
    float* __restrict__ parts,
    float* __restrict__ rowlogit) {
  extern __shared__ char ring_all[];  // 98304 = 4 waves x 3 x 8KB
  const int tid = threadIdx.x;
  const int lane = tid & 63;
  const int wv = tid >> 6;
  const int wrow = wv >> 1;   // 0..1
  const int wcol = wv & 1;    // 0..1
  const int ql = lane & 15;
  const int h = lane >> 4;    // 0..3

  const int bid = blockIdx.x;
  const int xcd = bid & 7;
  const int r0 = bid >> 3;                    // 0..31
  const int bm = (xcd >> 1) * 16 + (r0 & 15); // 0..63 (128-row tiles)
  const int sp = (xcd & 1) * 2 + (r0 >> 4);   // 0..3
  const int ntiles = (sp < 3) ? 21 : 20;

  char* ringW = ring_all + wv * 24576;  // wave-private 24KB ring
  const char* vb = ringW + lane * 16;   // per-lane ds_read base

  // ---- A fragments -> registers (32 coalesced dwordx4, pre-loop) ----
  bf16x8 aR[4][8];
  {
    const char* ab =
        (const char*)in2 + (size_t)(bm * 8 + wrow * 4) * 8192 + lane * 16;
#pragma unroll
    for (int mi = 0; mi < 4; ++mi)
#pragma unroll
      for (int kk = 0; kk < 8; ++kk)
        aR[mi][kk] = *(const bf16x8*)(ab + mi * 8192 + kk * 1024);
  }
  const int rowb = bm * 128 + wrow * 64 + h * 4;
  int4v lbl[4];
#pragma unroll
  for (int mi = 0; mi < 4; ++mi)
    lbl[mi] = *(const int4v*)(label + rowb + mi * 16);

  // B per-lane global source (wave's 64-col strip of its split's tiles)
  const char* sgS =
      (const char*)bank3 + (size_t)sp * 65536 + wcol * 32768 + lane * 16;

  // prologue: stage quarters 0,1 (16 ops in flight)
  STAGE8(sgS, 0);
  STAGE8(sgS + 2048, 8192);
  sgS += 4096;  // points at quarter G=2
  asm volatile("s_waitcnt vmcnt(8)" ::: "memory");  // stage(0) landed
  bf16x8 bA[8], bB[8];
  DSREAD8(bA, 0);  // frags(0)
  int roN = 8192, roS = 16384;

  const f32x4 vzero = {0.f, 0.f, 0.f, 0.f};
  const f32x4 vneg = {-1e30f, -1e30f, -1e30f, -1e30f};
  f32x4 acc[4][4], eacc[4][4];
  float se[4][4], cap[4][4];
#pragma unroll
  for (int a = 0; a < 4; ++a)
#pragma unroll
    for (int b = 0; b < 4; ++b) {
      eacc[a][b] = vneg;  // primes first-tile epilogue: exp2(-1e30) = 0
      se[a][b] = 0.f; cap[a][b] = -1e30f;
    }
  int pcol = -(1 << 20);  // no label matches negative cols
  int tcol = sp * 128 + wcol * 64 + ql;

  for (int i = 0; i < ntiles - 1; ++i) {
    QSTEP(0, bA, bB);
    QSTEP(1, bB, bA);
    QSTEP(2, bA, bB);
    QSTEP(3, bB, bA);
    // tile end: snapshot acc for next tile's interleaved epilogue
#pragma unroll
    for (int mi = 0; mi < 4; ++mi)
#pragma unroll
      for (int ni = 0; ni < 4; ++ni) eacc[mi][ni] = acc[mi][ni];
    pcol = tcol;
    tcol += NSPLIT * 128;
  }
  // ---- last tile (no staging beyond the end) ----
  QSTEP(0, bA, bB);
  QSTEP(1, bB, bA);
  // q2: no stage left; drain to get frags(NQ-1)
  asm volatile("s_waitcnt vmcnt(0)" ::: "memory");
  DSREAD8(bB, roN);
  asm volatile("s_waitcnt lgkmcnt(8)" ::: "memory");
  __builtin_amdgcn_sched_barrier(0);
  CLUSTER(2, bA);
  // q3: compute only
  asm volatile("s_waitcnt lgkmcnt(0)" ::: "memory");
  __builtin_amdgcn_sched_barrier(0);
  CLUSTER(3, bB);
  // flush the last tile's accumulators
#pragma unroll
  for (int ni = 0; ni < 4; ++ni) {
    const int ec = tcol + ni * 16;
#pragma unroll
    for (int mi = 0; mi < 4; ++mi)
#pragma unroll
      for (int r = 0; r < 4; ++r) {
        const float v = acc[mi][ni][r];
        se[mi][r] += __builtin_amdgcn_exp2f(v);
        if (lbl[mi][r] == ec) cap[mi][r] = v;
      }
  }

  // captured label logits (exactly one thread per labeled row matches)
#pragma unroll
  for (int mi = 0; mi < 4; ++mi)
#pragma unroll
    for (int r = 0; r < 4; ++r)
      if (cap[mi][r] > -1e29f) rowlogit[rowb + mi * 16 + r] = cap[mi][r];

  // reduce across the 16 column-lanes (ql) of each row group
#pragma unroll
  for (int mi = 0; mi < 4; ++mi)
#pragma unroll
    for (int r = 0; r < 4; ++r) {
      float v = se[mi][r];
      v += __shfl_xor(v, 1);
      v += __shfl_xor(v, 2);
      v += __shfl_xor(v, 4);
      v += __shfl_xor(v, 8);
      se[mi][r] = v;
    }
  if (ql == 0) {
    const int part = sp * 2 + wcol;  // deterministic partial slot, 0..7
#pragma unroll
    for (int mi = 0; mi < 4; ++mi) {
      f32x4 o = {se[mi][0], se[mi][1], se[mi][2], se[mi][3]};
      *(f32x4*)(parts + (size_t)part * NROWS + rowb + mi * 16) = o;
    }
  }
}

// ---------------------------------------------------------------------------
// reduce1: 32 blocks x 256 threads, one row per thread.
// tot = sum(parts) - PADCOLS; s = ln2*(log2(tot) - rowlogit) for valid rows.
// ---------------------------------------------------------------------------
__global__ void reduce1_kernel(const float* __restrict__ parts,
                               const float* __restrict__ rowlogit,
                               const int* __restrict__ label,
                               float* __restrict__ blk) {
  const int r = blockIdx.x * 256 + threadIdx.x;
  float s = 0.0f, c = 0.0f;
  if (label[r] != IGNORE_IDX) {
    float tot = 0.0f;
#pragma unroll
    for (int p = 0; p < NPARTS; ++p) tot += parts[p * NROWS + r];
    tot -= (float)PADCOLS;
    s = LN2f * (__builtin_log2f(tot) - rowlogit[r]);
    c = 1.0f;
  }
#pragma unroll
  for (int m = 1; m < 64; m <<= 1) {
    s += __shfl_xor(s, m);
    c += __shfl_xor(c, m);
  }
  __shared__ float ss[4], sc[4];
  const int wv = threadIdx.x >> 6, lane = threadIdx.x & 63;
  if (lane == 0) { ss[wv] = s; sc[wv] = c; }
  __syncthreads();
  if (threadIdx.x == 0) {
    blk[blockIdx.x * 2 + 0] = ss[0] + ss[1] + ss[2] + ss[3];
    blk[blockIdx.x * 2 + 1] = sc[0] + sc[1] + sc[2] + sc[3];
  }
}

__global__ void reduce2_kernel(const float* __restrict__ blk,
                               float* __restrict__ out) {
  const int lane = threadIdx.x;
  float s = (lane < 32) ? blk[lane * 2 + 0] : 0.0f;
  float c = (lane < 32) ? blk[lane * 2 + 1] : 0.0f;
#pragma unroll
  for (int m = 1; m < 32; m <<= 1) {
    s += __shfl_xor(s, m);
    c += __shfl_xor(c, m);
  }
  if (lane == 0) out[0] = s / fmaxf(c, 1.0f);
}

extern "C" void kernel_launch(void* const* d_in, const int* in_sizes, int n_in,
                              void* d_out, int out_size, void* d_ws,
                              size_t ws_size, hipStream_t stream) {
  const float* inputs = (const float*)d_in[0];
  const int* label = (const int*)d_in[1];
  // d_in[2] = ious (unused by the reference loss)
  const float* lut = (const float*)d_in[3];
  const float* cq = (const float*)d_in[4];
  const float* rel = (const float*)d_in[5];
  float* out = (float*)d_out;
  char* ws = (char*)d_ws;
  if (ws_size < WS_NEED) return;

  unsigned short* in2 = (unsigned short*)(ws + WS_INBF);
  unsigned short* bank3 = (unsigned short*)(ws + WS_BANK);
  float* parts = (float*)(ws + WS_PARTS);
  float* rowlogit = (float*)(ws + WS_RLOGIT);
  float* blk = (float*)(ws + WS_BLK);

  hipFuncSetAttribute((const void*)oim_main_kernel,
                      hipFuncAttributeMaxDynamicSharedMemorySize, 98304);

  prep_kernel<<<dim3(1024), dim3(256), 0, stream>>>(inputs, lut, cq, rel,
                                                    in2, bank3);
  oim_main_kernel<<<dim3(64 * NSPLIT), dim3(256), 98304, stream>>>(
      in2, bank3, label, parts, rowlogit);
  reduce1_kernel<<<dim3(32), dim3(256), 0, stream>>>(parts, rowlogit, label,
                                                     blk);
  reduce2_kernel<<<dim3(1), dim3(64), 0, stream>>>(blk, out);
}

// Round 9
// 65.784 us; speedup vs baseline: 2.4340x; 1.0211x over previous
//
#include <hip/hip_runtime.h>
#include <stdint.h>

#define NROWS 8192
#define DDIM 256
#define NPIDS 5532
#define NCQ 5000
#define LCOLS 10532            // NPIDS + NCQ
#define IGNORE_IDX 5554
#define NT 83                  // ceil(10532/128)
#define LPAD (NT * 128)        // 10624
#define NSPLIT 4
#define NPARTS (NSPLIT * 2)    // 8 partial slots per row
#define PADCOLS (LPAD - LCOLS) // 92, each contributes exp2(0)=1 exactly
#define TSTEP (NSPLIT * 65536) // 262144 B between consecutive tiles of a split
#define OIM_SCALE 30.0f
#define LOG2E 1.4426950408889634f
#define LN2f 0.6931471805599453f

using f32x4 = __attribute__((ext_vector_type(4))) float;
using bf16x8 = __attribute__((ext_vector_type(8))) __bf16;
using ushort8 = __attribute__((ext_vector_type(8))) unsigned short;

// ws layout (bytes)
#define WS_INBF 0u             // 8192*256*2   = 4,194,304 (frag-order bf16)
#define WS_BANK 4194304u       // 10624*256*2  = 5,439,488 (frag-order, rse-scaled)
#define WS_PARTS 9633792u      // 8*8192*4     = 262,144
#define WS_RLOGIT 9895936u     // 8192*4       = 32,768
#define WS_BLK 9928704u        // 32*2*4       = 256
#define WS_NEED 9928960u

__device__ __forceinline__ unsigned short f2bf(float f) {
  union { float f; uint32_t u; } v; v.f = f;
  uint32_t u = v.u;
  uint32_t r = (u + 0x7FFFu + ((u >> 16) & 1u)) >> 16;  // RNE
  return (unsigned short)r;
}

__device__ __forceinline__ void async16(const void* g, void* l) {
  __builtin_amdgcn_global_load_lds(
      (const __attribute__((address_space(1))) uint32_t*)g,
      (__attribute__((address_space(3))) uint32_t*)l, 16, 0, 0);
}

// ---------------------------------------------------------------------------
// prep (unchanged, proven): store A and B in MFMA fragment-consumption order
// so every main-loop operand transfer is ONE coalesced 1KB op:
//   A byte(R,k)  = (R>>4)*8192 + (k>>5)*1024 + ((k>>3)&3)*256 + (R&15)*16
//   B byte(R,k)  = (R>>7)*65536 + ((R>>4)&7)*8192 + (k>>5)*1024
//                  + ((k>>3)&3)*256 + (R&15)*16
// B row R scaled by 30*rel[R]*log2e BEFORE bf16 quantization; pad rows = 0.
// ---------------------------------------------------------------------------
__global__ void prep_kernel(const float* __restrict__ inputs,
                            const float* __restrict__ lut,
                            const float* __restrict__ cq,
                            const float* __restrict__ rel,
                            unsigned short* __restrict__ in2,
                            unsigned short* __restrict__ bank3) {
  const int GIN = NROWS * (DDIM / 8);   // 262144 dst granules (16B)
  const int GBK = LPAD * (DDIM / 8);    // 339968 dst granules
  const int total = GIN + GBK;
  for (int d = blockIdx.x * blockDim.x + threadIdx.x; d < total;
       d += gridDim.x * blockDim.x) {
    const float* src = nullptr;
    unsigned short* dst;
    float scale = 1.0f;
    bool zero = false;
    if (d < GIN) {
      const int R = ((d >> 9) << 4) | (d & 15);
      const int c8 = (((d >> 6) & 7) << 2) | ((d >> 4) & 3);
      src = inputs + R * DDIM + c8 * 8;
      dst = in2 + (size_t)d * 8;
    } else {
      const int b = d - GIN;
      const int R = ((b >> 12) << 7) | (((b >> 9) & 7) << 4) | (b & 15);
      const int c8 = (((b >> 6) & 7) << 2) | ((b >> 4) & 3);
      dst = bank3 + (size_t)b * 8;
      if (R < NPIDS) src = lut + (size_t)R * DDIM + c8 * 8;
      else if (R < LCOLS) src = cq + (size_t)(R - NPIDS) * DDIM + c8 * 8;
      else zero = true;
      if (!zero) scale = OIM_SCALE * LOG2E * rel[R];
    }
    ushort8 o = {0, 0, 0, 0, 0, 0, 0, 0};
    if (!zero) {
      const f32x4* s4 = (const f32x4*)src;
      f32x4 v0 = s4[0], v1 = s4[1];
      o[0] = f2bf(v0[0] * scale); o[1] = f2bf(v0[1] * scale);
      o[2] = f2bf(v0[2] * scale); o[3] = f2bf(v0[3] * scale);
      o[4] = f2bf(v1[0] * scale); o[5] = f2bf(v1[1] * scale);
      o[6] = f2bf(v1[2] * scale); o[7] = f2bf(v1[3] * scale);
    }
    *(ushort8*)dst = o;
  }
}

// ---------------------------------------------------------------------------
// main: fused GEMM + sum-of-exp. ZERO BARRIERS, within-wave pipeline,
// DEPTH-2-QUARTER prefetch (ring of 4), NO label work in the hot loop.
// 256 blocks = 1/CU, 4 independent waves = 1 wave/SIMD, full VGPR budget.
// Wave tile 64x64 (4mi x 4ni of 16x16x32); A: 128-VGPR persistent frags.
// B: wave-private 4 x 8KB LDS ring (32KB/wave, 128KB/block). Per quarter Q:
//   stage(Q+3) [8 async16] -> vmcnt(16) [stage(Q+1) landed, issued 2 quarters
//   ago ~1300cy > L2/L3 latency] -> ds_read frags(Q+1) [8 x b128]
//   -> lgkmcnt(8)+sched_barrier [frags(Q) resident]
//   -> 32 MFMA on frags(Q) + prev-tile exp2 epilogue (16 exp2+add) interleaved.
// Main loop is branch-free (ahead >= 4 always); tail quarters explicit.
// XCD-aligned decode: per-XCD set = A 1MB + B 2.7MB, L2-resident.
// ---------------------------------------------------------------------------
#define STAGE8(SRC, DSTOFF)                                               \
  do {                                                                    \
    const char* _s = (SRC);                                               \
    char* _d = ringW + (DSTOFF);                                          \
    _Pragma("unroll") for (int _j = 0; _j < 8; ++_j)                      \
      async16(_s + (_j >> 1) * 8192 + (_j & 1) * 1024, _d + _j * 1024);   \
  } while (0)

#define DSREAD8(BANK, ROFF)                                               \
  do {                                                                    \
    const char* _p = vb + (ROFF);                                         \
    _Pragma("unroll") for (int _f = 0; _f < 8; ++_f)                      \
      BANK[_f] =                                                          \
          *(const bf16x8*)(_p + (_f >> 1) * 2048 + (_f & 1) * 1024);      \
  } while (0)

#define CLUSTER(Qq, BC)                                                   \
  do {                                                                    \
    _Pragma("unroll") for (int _kk = 0; _kk < 2; ++_kk)                   \
      _Pragma("unroll") for (int _mi = 0; _mi < 4; ++_mi) {               \
        _Pragma("unroll") for (int _ni = 0; _ni < 4; ++_ni)               \
          acc[_mi][_ni] = __builtin_amdgcn_mfma_f32_16x16x32_bf16(        \
              aR[_mi][(Qq) * 2 + _kk], BC[_ni * 2 + _kk],                 \
              ((Qq) == 0 && _kk == 0) ? vzero : acc[_mi][_ni], 0, 0, 0);  \
        se[_mi][_kk * 2] +=                                               \
            __builtin_amdgcn_exp2f(eacc[_mi][(Qq)][_kk * 2]);             \
        se[_mi][_kk * 2 + 1] +=                                           \
            __builtin_amdgcn_exp2f(eacc[_mi][(Qq)][_kk * 2 + 1]);         \
      }                                                                   \
  } while (0)

#define QSTEP(Qq, BC, BN)                                                 \
  do {                                                                    \
    STAGE8(sgS, roS);                                                     \
    sgS += ((Qq) == 0) ? (TSTEP - 6144) : 2048;                           \
    roS += 8192; if (roS >= 32768) roS -= 32768;                          \
    asm volatile("s_waitcnt vmcnt(16)" ::: "memory");                     \
    DSREAD8(BN, roN);                                                     \
    roN += 8192; if (roN >= 32768) roN -= 32768;                          \
    asm volatile("s_waitcnt lgkmcnt(8)" ::: "memory");                    \
    __builtin_amdgcn_sched_barrier(0);                                    \
    CLUSTER(Qq, BC);                                                      \
  } while (0)

__global__ __launch_bounds__(256, 1) void oim_main_kernel(
    const unsigned short* __restrict__ in2,
    const unsigned short* __restrict__ bank3,
    float* __restrict__ parts) {
  extern __shared__ char ring_all[];  // 131072 = 4 waves x 4 x 8KB
  const int tid = threadIdx.x;
  const int lane = tid & 63;
  const int wv = tid >> 6;
  const int wrow = wv >> 1;   // 0..1
  const int wcol = wv & 1;    // 0..1
  const int ql = lane & 15;
  const int h = lane >> 4;    // 0..3

  const int bid = blockIdx.x;
  const int xcd = bid & 7;
  const int r0 = bid >> 3;                    // 0..31
  const int bm = (xcd >> 1) * 16 + (r0 & 15); // 0..63 (128-row tiles)
  const int sp = (xcd & 1) * 2 + (r0 >> 4);   // 0..3
  const int ntiles = (sp < 3) ? 21 : 20;

  char* ringW = ring_all + wv * 32768;  // wave-private 32KB ring
  const char* vb = ringW + lane * 16;   // per-lane ds_read base

  // ---- A fragments -> registers (32 coalesced dwordx4, pre-loop) ----
  bf16x8 aR[4][8];
  {
    const char* ab =
        (const char*)in2 + (size_t)(bm * 8 + wrow * 4) * 8192 + lane * 16;
#pragma unroll
    for (int mi = 0; mi < 4; ++mi)
#pragma unroll
      for (int kk = 0; kk < 8; ++kk)
        aR[mi][kk] = *(const bf16x8*)(ab + mi * 8192 + kk * 1024);
  }
  const int rowb = bm * 128 + wrow * 64 + h * 4;

  asm volatile("" ::: "memory");  // pin: A-loads before staging (vmcnt order)

  // B per-lane global source (wave's 64-col strip of its split's tiles)
  const char* sgS =
      (const char*)bank3 + (size_t)sp * 65536 + wcol * 32768 + lane * 16;

  // prologue: stage quarters 0,1,2 (24 ops in flight after A's 32)
  STAGE8(sgS, 0);
  STAGE8(sgS + 2048, 8192);
  STAGE8(sgS + 4096, 16384);
  sgS += 6144;  // points at quarter 3
  asm volatile("s_waitcnt vmcnt(16)" ::: "memory");  // A + stage(0) landed
  bf16x8 bA[8], bB[8];
  DSREAD8(bA, 0);  // frags(0)
  int roN = 8192, roS = 24576;

  const f32x4 vzero = {0.f, 0.f, 0.f, 0.f};
  const f32x4 vneg = {-1e30f, -1e30f, -1e30f, -1e30f};
  f32x4 acc[4][4], eacc[4][4];
  float se[4][4];
#pragma unroll
  for (int a = 0; a < 4; ++a)
#pragma unroll
    for (int b = 0; b < 4; ++b) {
      eacc[a][b] = vneg;  // primes first-tile epilogue: exp2(-1e30) = 0
      se[a][b] = 0.f;
    }

  for (int i = 0; i < ntiles - 1; ++i) {
    QSTEP(0, bA, bB);
    QSTEP(1, bB, bA);
    QSTEP(2, bA, bB);
    QSTEP(3, bB, bA);
    // tile end: snapshot acc for next tile's interleaved epilogue
#pragma unroll
    for (int mi = 0; mi < 4; ++mi)
#pragma unroll
      for (int ni = 0; ni < 4; ++ni) eacc[mi][ni] = acc[mi][ni];
  }
  // ---- last tile: stage final quarter, then drain the pipeline ----
  STAGE8(sgS, roS);  // quarter NQ-1
  asm volatile("s_waitcnt vmcnt(16)" ::: "memory");
  DSREAD8(bB, roN);
  roN += 8192; if (roN >= 32768) roN -= 32768;
  asm volatile("s_waitcnt lgkmcnt(8)" ::: "memory");
  __builtin_amdgcn_sched_barrier(0);
  CLUSTER(0, bA);
  asm volatile("s_waitcnt vmcnt(8)" ::: "memory");
  DSREAD8(bA, roN);
  roN += 8192; if (roN >= 32768) roN -= 32768;
  asm volatile("s_waitcnt lgkmcnt(8)" ::: "memory");
  __builtin_amdgcn_sched_barrier(0);
  CLUSTER(1, bB);
  asm volatile("s_waitcnt vmcnt(0)" ::: "memory");
  DSREAD8(bB, roN);
  asm volatile("s_waitcnt lgkmcnt(8)" ::: "memory");
  __builtin_amdgcn_sched_barrier(0);
  CLUSTER(2, bA);
  asm volatile("s_waitcnt lgkmcnt(0)" ::: "memory");
  __builtin_amdgcn_sched_barrier(0);
  CLUSTER(3, bB);
  // flush the last tile's accumulators
#pragma unroll
  for (int mi = 0; mi < 4; ++mi)
#pragma unroll
    for (int ni = 0; ni < 4; ++ni)
#pragma unroll
      for (int r = 0; r < 4; ++r)
        se[mi][r] += __builtin_amdgcn_exp2f(acc[mi][ni][r]);

  // reduce across the 16 column-lanes (ql) of each row group
#pragma unroll
  for (int mi = 0; mi < 4; ++mi)
#pragma unroll
    for (int r = 0; r < 4; ++r) {
      float v = se[mi][r];
      v += __shfl_xor(v, 1);
      v += __shfl_xor(v, 2);
      v += __shfl_xor(v, 4);
      v += __shfl_xor(v, 8);
      se[mi][r] = v;
    }
  if (ql == 0) {
    const int part = sp * 2 + wcol;  // deterministic partial slot, 0..7
#pragma unroll
    for (int mi = 0; mi < 4; ++mi) {
      f32x4 o = {se[mi][0], se[mi][1], se[mi][2], se[mi][3]};
      *(f32x4*)(parts + (size_t)part * NROWS + rowb + mi * 16) = o;
    }
  }
}

// ---------------------------------------------------------------------------
// exact fp32 label logit: one wave per row, gather bank row by label
// (removed from the hot loop -- the per-element cmp+cndmask there cost ~10us).
// ---------------------------------------------------------------------------
__global__ void label_logit_kernel(const float* __restrict__ inputs,
                                   const int* __restrict__ label,
                                   const float* __restrict__ lut,
                                   const float* __restrict__ cq,
                                   const float* __restrict__ rel,
                                   float* __restrict__ rowlogit) {
  const int lane = threadIdx.x & 63;
  const int wv = threadIdx.x >> 6;
  const int row = blockIdx.x * 4 + wv;
  if (row >= NROWS) return;
  const int l = label[row];
  float out = 0.0f;
  if (l != IGNORE_IDX && l >= 0 && l < LCOLS) {
    const float* bk = (l < NPIDS) ? (lut + (size_t)l * DDIM)
                                  : (cq + (size_t)(l - NPIDS) * DDIM);
    f32x4 a = *(const f32x4*)(inputs + (size_t)row * DDIM + lane * 4);
    f32x4 b = *(const f32x4*)(bk + lane * 4);
    float d = a[0] * b[0] + a[1] * b[1] + a[2] * b[2] + a[3] * b[3];
#pragma unroll
    for (int m = 1; m < 64; m <<= 1) d += __shfl_xor(d, m);
    out = OIM_SCALE * rel[l] * d;
  }
  if (lane == 0) rowlogit[row] = out;
}

// ---------------------------------------------------------------------------
// reduce1: 32 blocks x 256 threads, one row per thread.
// tot = sum(parts) - PADCOLS; s = ln2*log2(tot) - rowlogit for valid rows.
// ---------------------------------------------------------------------------
__global__ void reduce1_kernel(const float* __restrict__ parts,
                               const float* __restrict__ rowlogit,
                               const int* __restrict__ label,
                               float* __restrict__ blk) {
  const int r = blockIdx.x * 256 + threadIdx.x;
  float s = 0.0f, c = 0.0f;
  if (label[r] != IGNORE_IDX) {
    float tot = 0.0f;
#pragma unroll
    for (int p = 0; p < NPARTS; ++p) tot += parts[p * NROWS + r];
    tot -= (float)PADCOLS;
    s = LN2f * __builtin_log2f(tot) - rowlogit[r];
    c = 1.0f;
  }
#pragma unroll
  for (int m = 1; m < 64; m <<= 1) {
    s += __shfl_xor(s, m);
    c += __shfl_xor(c, m);
  }
  __shared__ float ss[4], sc[4];
  const int wv = threadIdx.x >> 6, lane = threadIdx.x & 63;
  if (lane == 0) { ss[wv] = s; sc[wv] = c; }
  __syncthreads();
  if (threadIdx.x == 0) {
    blk[blockIdx.x * 2 + 0] = ss[0] + ss[1] + ss[2] + ss[3];
    blk[blockIdx.x * 2 + 1] = sc[0] + sc[1] + sc[2] + sc[3];
  }
}

__global__ void reduce2_kernel(const float* __restrict__ blk,
                               float* __restrict__ out) {
  const int lane = threadIdx.x;
  float s = (lane < 32) ? blk[lane * 2 + 0] : 0.0f;
  float c = (lane < 32) ? blk[lane * 2 + 1] : 0.0f;
#pragma unroll
  for (int m = 1; m < 32; m <<= 1) {
    s += __shfl_xor(s, m);
    c += __shfl_xor(c, m);
  }
  if (lane == 0) out[0] = s / fmaxf(c, 1.0f);
}

extern "C" void kernel_launch(void* const* d_in, const int* in_sizes, int n_in,
                              void* d_out, int out_size, void* d_ws,
                              size_t ws_size, hipStream_t stream) {
  const float* inputs = (const float*)d_in[0];
  const int* label = (const int*)d_in[1];
  // d_in[2] = ious (unused by the reference loss)
  const float* lut = (const float*)d_in[3];
  const float* cq = (const float*)d_in[4];
  const float* rel = (const float*)d_in[5];
  float* out = (float*)d_out;
  char* ws = (char*)d_ws;
  if (ws_size < WS_NEED) return;

  unsigned short* in2 = (unsigned short*)(ws + WS_INBF);
  unsigned short* bank3 = (unsigned short*)(ws + WS_BANK);
  float* parts = (float*)(ws + WS_PARTS);
  float* rowlogit = (float*)(ws + WS_RLOGIT);
  float* blk = (float*)(ws + WS_BLK);

  hipFuncSetAttribute((const void*)oim_main_kernel,
                      hipFuncAttributeMaxDynamicSharedMemorySize, 131072);

  prep_kernel<<<dim3(1024), dim3(256), 0, stream>>>(inputs, lut, cq, rel,
                                                    in2, bank3);
  label_logit_kernel<<<dim3(2048), dim3(256), 0, stream>>>(inputs, label, lut,
                                                           cq, rel, rowlogit);
  oim_main_kernel<<<dim3(64 * NSPLIT), dim3(256), 131072, stream>>>(
      in2, bank3, parts);
  reduce1_kernel<<<dim3(32), dim3(256), 0, stream>>>(parts, rowlogit, label,
                                                     blk);
  reduce2_kernel<<<dim3(1), dim3(64), 0, stream>>>(blk, out);
}

// Round 10
// 60.735 us; speedup vs baseline: 2.6363x; 1.0831x over previous
//
#include <hip/hip_runtime.h>
#include <stdint.h>

#define NROWS 8192
#define DDIM 256
#define NPIDS 5532
#define NCQ 5000
#define LCOLS 10532            // NPIDS + NCQ
#define IGNORE_IDX 5554
#define NT 83                  // ceil(10532/128)
#define LPAD (NT * 128)        // 10624
#define NSPLIT 8
#define NPARTS (NSPLIT * 2)    // 16 partial slots per row
#define PADCOLS (LPAD - LCOLS) // 92, each contributes exp2(0)=1 exactly
#define TSTEP (NSPLIT * 65536) // 524288 B between consecutive tiles of a split
#define OIM_SCALE 30.0f
#define LOG2E 1.4426950408889634f
#define LN2f 0.6931471805599453f

using f32x4 = __attribute__((ext_vector_type(4))) float;
using bf16x8 = __attribute__((ext_vector_type(8))) __bf16;
using ushort8 = __attribute__((ext_vector_type(8))) unsigned short;

// ws layout (bytes)
#define WS_INBF 0u             // 8192*256*2   = 4,194,304 (frag-order bf16)
#define WS_BANK 4194304u       // 10624*256*2  = 5,439,488 (frag-order, rse-scaled)
#define WS_PARTS 9633792u      // 16*8192*4    = 524,288
#define WS_RLOGIT 10158080u    // 8192*4       = 32,768
#define WS_BLK 10190848u       // 32*2*4       = 256
#define WS_NEED 10191104u

__device__ __forceinline__ unsigned short f2bf(float f) {
  union { float f; uint32_t u; } v; v.f = f;
  uint32_t u = v.u;
  uint32_t r = (u + 0x7FFFu + ((u >> 16) & 1u)) >> 16;  // RNE
  return (unsigned short)r;
}

__device__ __forceinline__ void async16(const void* g, void* l) {
  __builtin_amdgcn_global_load_lds(
      (const __attribute__((address_space(1))) uint32_t*)g,
      (__attribute__((address_space(3))) uint32_t*)l, 16, 0, 0);
}

// ---------------------------------------------------------------------------
// prep (unchanged, proven): store A and B in MFMA fragment-consumption order
// so every main-loop operand transfer is ONE coalesced 1KB op:
//   A byte(R,k)  = (R>>4)*8192 + (k>>5)*1024 + ((k>>3)&3)*256 + (R&15)*16
//   B byte(R,k)  = (R>>7)*65536 + ((R>>4)&7)*8192 + (k>>5)*1024
//                  + ((k>>3)&3)*256 + (R&15)*16
// B row R scaled by 30*rel[R]*log2e BEFORE bf16 quantization; pad rows = 0.
// ---------------------------------------------------------------------------
__global__ void prep_kernel(const float* __restrict__ inputs,
                            const float* __restrict__ lut,
                            const float* __restrict__ cq,
                            const float* __restrict__ rel,
                            unsigned short* __restrict__ in2,
                            unsigned short* __restrict__ bank3) {
  const int GIN = NROWS * (DDIM / 8);   // 262144 dst granules (16B)
  const int GBK = LPAD * (DDIM / 8);    // 339968 dst granules
  const int total = GIN + GBK;
  for (int d = blockIdx.x * blockDim.x + threadIdx.x; d < total;
       d += gridDim.x * blockDim.x) {
    const float* src = nullptr;
    unsigned short* dst;
    float scale = 1.0f;
    bool zero = false;
    if (d < GIN) {
      const int R = ((d >> 9) << 4) | (d & 15);
      const int c8 = (((d >> 6) & 7) << 2) | ((d >> 4) & 3);
      src = inputs + R * DDIM + c8 * 8;
      dst = in2 + (size_t)d * 8;
    } else {
      const int b = d - GIN;
      const int R = ((b >> 12) << 7) | (((b >> 9) & 7) << 4) | (b & 15);
      const int c8 = (((b >> 6) & 7) << 2) | ((b >> 4) & 3);
      dst = bank3 + (size_t)b * 8;
      if (R < NPIDS) src = lut + (size_t)R * DDIM + c8 * 8;
      else if (R < LCOLS) src = cq + (size_t)(R - NPIDS) * DDIM + c8 * 8;
      else zero = true;
      if (!zero) scale = OIM_SCALE * LOG2E * rel[R];
    }
    ushort8 o = {0, 0, 0, 0, 0, 0, 0, 0};
    if (!zero) {
      const f32x4* s4 = (const f32x4*)src;
      f32x4 v0 = s4[0], v1 = s4[1];
      o[0] = f2bf(v0[0] * scale); o[1] = f2bf(v0[1] * scale);
      o[2] = f2bf(v0[2] * scale); o[3] = f2bf(v0[3] * scale);
      o[4] = f2bf(v1[0] * scale); o[5] = f2bf(v1[1] * scale);
      o[6] = f2bf(v1[2] * scale); o[7] = f2bf(v1[3] * scale);
    }
    *(ushort8*)dst = o;
  }
}

// ---------------------------------------------------------------------------
// main: fused GEMM + sum-of-exp. "m201-lite": BM=256 to amortize staging.
// 256 blocks = 1/CU, 512 threads = 8 waves (4 wrow x 2 wcol) = 2 waves/SIMD.
// Block: 256 rows x (10-11 col-tiles of 128), K=256. A register-persistent
// (aR 128 VGPR/wave, loaded once). B: SHARED LDS, ring of 4 x 16KB K-64
// phase-chunks, staged cooperatively (all 512 threads, 2 async16 each),
// depth-2 prefetch, counted `s_waitcnt vmcnt(4)` + ONE raw s_barrier per
// phase (~1242 cyc cadence). Staging demand = 64 B/MFMA = 13 B/cyc/CU,
// 3x less than round 9 (the measured ~33% wall tracked staged-bytes/MFMA).
// sp = bid&7 = XCD id -> per-XCD B slice 0.66-0.72MB, L2-resident.
// ---------------------------------------------------------------------------
#define STG(PP)                                                           \
  do {                                                                    \
    char* _d = dT + (((PP) + 2) & 3) * 16384;                             \
    async16(sgP, _d);                                                     \
    async16(sgP + 32768, _d + 8192);                                      \
    sgP += ((PP) == 1) ? (TSTEP - 6144) : 2048;                           \
  } while (0)

#define PHASE(PP, VMN)                                                    \
  do {                                                                    \
    asm volatile("s_waitcnt vmcnt(" #VMN ")" ::: "memory");               \
    asm volatile("s_barrier" ::: "memory");                               \
    const char* _c = rB + (PP) * 16384;                                   \
    bf16x8 bF[4][2];                                                      \
    _Pragma("unroll") for (int _ni = 0; _ni < 4; ++_ni)                   \
      _Pragma("unroll") for (int _kl = 0; _kl < 2; ++_kl)                 \
        bF[_ni][_kl] = *(const bf16x8*)(_c + _ni * 2048 + _kl * 1024);    \
    asm volatile("s_waitcnt lgkmcnt(0)" ::: "memory");                    \
    __builtin_amdgcn_sched_barrier(0);                                    \
    __builtin_amdgcn_s_setprio(1);                                        \
    _Pragma("unroll") for (int _kl = 0; _kl < 2; ++_kl)                   \
      _Pragma("unroll") for (int _mi = 0; _mi < 4; ++_mi)                 \
        _Pragma("unroll") for (int _ni = 0; _ni < 4; ++_ni)               \
          acc[_mi][_ni] = __builtin_amdgcn_mfma_f32_16x16x32_bf16(        \
              aR[_mi][(PP) * 2 + _kl], bF[_ni][_kl],                      \
              ((PP) == 0 && _kl == 0) ? vzero : acc[_mi][_ni], 0, 0, 0);  \
    __builtin_amdgcn_s_setprio(0);                                        \
  } while (0)

__global__ __launch_bounds__(512, 2) void oim_main_kernel(
    const unsigned short* __restrict__ in2,
    const unsigned short* __restrict__ bank3,
    float* __restrict__ parts) {
  extern __shared__ char ring[];  // 65536 = 4 slots x 16KB
  const int tid = threadIdx.x;
  const int lane = tid & 63;
  const int wv = tid >> 6;    // 0..7
  const int wrow = wv >> 1;   // 0..3
  const int wcol = wv & 1;    // 0..1
  const int ql = lane & 15;
  const int h = lane >> 4;    // 0..3

  const int bid = blockIdx.x;
  const int sp = bid & 7;     // == XCD id under round-robin dispatch
  const int bm = bid >> 3;    // 0..31 (256-row blocks)
  const int ntiles = (sp < 3) ? 11 : 10;  // 3*11 + 5*10 = 83

  // ---- A fragments -> registers (32 coalesced dwordx4, once) ----
  bf16x8 aR[4][8];
  {
    const char* ab =
        (const char*)in2 + (size_t)(bm * 16 + wrow * 4) * 8192 + lane * 16;
#pragma unroll
    for (int mi = 0; mi < 4; ++mi)
#pragma unroll
      for (int kk = 0; kk < 8; ++kk)
        aR[mi][kk] = *(const bf16x8*)(ab + mi * 8192 + kk * 1024);
  }
  const int rowb = bm * 256 + wrow * 64 + h * 4;

  asm volatile("" ::: "memory");  // pin: A-loads precede staging (vmcnt order)

  // staging: per-thread src/dst. LDS slot layout = [colblk 8][kkl 2][lane]:
  //   dst half0 o=tid*16 <-> colblk=tid>>7, within=(tid&127)*16; half1 +8192
  //   src = tile + colblk*8192 + pp*2048 + within   (second half +32768)
  const char* sgT = (const char*)bank3 + (size_t)sp * 65536 +
                    (tid >> 7) * 8192 + (tid & 127) * 16;
  char* dT = ring + tid * 16;

  // prologue: stage (tile0,pp0)->slot0, (tile0,pp1)->slot1
  async16(sgT, dT);
  async16(sgT + 32768, dT + 8192);
  asm volatile("" ::: "memory");
  async16(sgT + 2048, dT + 16384);
  async16(sgT + 2048 + 32768, dT + 16384 + 8192);
  asm volatile("" ::: "memory");
  const char* sgP = sgT + 4096;  // next stage: (tile0, pp2)

  // per-wave LDS read base (its wcol 64-col strip)
  const char* rB = ring + (wcol * 4) * 2048 + lane * 16;

  const f32x4 vzero = {0.f, 0.f, 0.f, 0.f};
  f32x4 acc[4][4];
  float se[4][4];
#pragma unroll
  for (int a = 0; a < 4; ++a)
#pragma unroll
    for (int b = 0; b < 4; ++b) se[a][b] = 0.f;

  for (int t = 0; t < ntiles - 1; ++t) {
    STG(0); PHASE(0, 4);
    STG(1); PHASE(1, 4);
    STG(2); PHASE(2, 4);
    STG(3); PHASE(3, 4);
    // tile epilogue: pure exp2+add (B pre-scaled by rse; pad cols -> +1.0)
#pragma unroll
    for (int mi = 0; mi < 4; ++mi)
#pragma unroll
      for (int ni = 0; ni < 4; ++ni)
#pragma unroll
        for (int r = 0; r < 4; ++r)
          se[mi][r] += __builtin_amdgcn_exp2f(acc[mi][ni][r]);
  }
  // ---- last tile: stages for its first two phases, then drain ----
  STG(0); PHASE(0, 4);
  STG(1); PHASE(1, 4);
  PHASE(2, 2);
  PHASE(3, 0);
#pragma unroll
  for (int mi = 0; mi < 4; ++mi)
#pragma unroll
    for (int ni = 0; ni < 4; ++ni)
#pragma unroll
      for (int r = 0; r < 4; ++r)
        se[mi][r] += __builtin_amdgcn_exp2f(acc[mi][ni][r]);

  // reduce across the 16 column-lanes (ql) of each row group
#pragma unroll
  for (int mi = 0; mi < 4; ++mi)
#pragma unroll
    for (int r = 0; r < 4; ++r) {
      float v = se[mi][r];
      v += __shfl_xor(v, 1);
      v += __shfl_xor(v, 2);
      v += __shfl_xor(v, 4);
      v += __shfl_xor(v, 8);
      se[mi][r] = v;
    }
  if (ql == 0) {
    const int part = sp * 2 + wcol;  // deterministic partial slot, 0..15
#pragma unroll
    for (int mi = 0; mi < 4; ++mi) {
      f32x4 o = {se[mi][0], se[mi][1], se[mi][2], se[mi][3]};
      *(f32x4*)(parts + (size_t)part * NROWS + rowb + mi * 16) = o;
    }
  }
}

// ---------------------------------------------------------------------------
// exact fp32 label logit: one wave per row, gather bank row by label.
// ---------------------------------------------------------------------------
__global__ void label_logit_kernel(const float* __restrict__ inputs,
                                   const int* __restrict__ label,
                                   const float* __restrict__ lut,
                                   const float* __restrict__ cq,
                                   const float* __restrict__ rel,
                                   float* __restrict__ rowlogit) {
  const int lane = threadIdx.x & 63;
  const int wv = threadIdx.x >> 6;
  const int row = blockIdx.x * 4 + wv;
  if (row >= NROWS) return;
  const int l = label[row];
  float out = 0.0f;
  if (l != IGNORE_IDX && l >= 0 && l < LCOLS) {
    const float* bk = (l < NPIDS) ? (lut + (size_t)l * DDIM)
                                  : (cq + (size_t)(l - NPIDS) * DDIM);
    f32x4 a = *(const f32x4*)(inputs + (size_t)row * DDIM + lane * 4);
    f32x4 b = *(const f32x4*)(bk + lane * 4);
    float d = a[0] * b[0] + a[1] * b[1] + a[2] * b[2] + a[3] * b[3];
#pragma unroll
    for (int m = 1; m < 64; m <<= 1) d += __shfl_xor(d, m);
    out = OIM_SCALE * rel[l] * d;
  }
  if (lane == 0) rowlogit[row] = out;
}

// ---------------------------------------------------------------------------
// reduce1: 32 blocks x 256 threads, one row per thread.
// tot = sum(parts) - PADCOLS; s = ln2*log2(tot) - rowlogit for valid rows.
// ---------------------------------------------------------------------------
__global__ void reduce1_kernel(const float* __restrict__ parts,
                               const float* __restrict__ rowlogit,
                               const int* __restrict__ label,
                               float* __restrict__ blk) {
  const int r = blockIdx.x * 256 + threadIdx.x;
  float s = 0.0f, c = 0.0f;
  if (label[r] != IGNORE_IDX) {
    float tot = 0.0f;
#pragma unroll
    for (int p = 0; p < NPARTS; ++p) tot += parts[p * NROWS + r];
    tot -= (float)PADCOLS;
    s = LN2f * __builtin_log2f(tot) - rowlogit[r];
    c = 1.0f;
  }
#pragma unroll
  for (int m = 1; m < 64; m <<= 1) {
    s += __shfl_xor(s, m);
    c += __shfl_xor(c, m);
  }
  __shared__ float ss[4], sc[4];
  const int wv = threadIdx.x >> 6, lane = threadIdx.x & 63;
  if (lane == 0) { ss[wv] = s; sc[wv] = c; }
  __syncthreads();
  if (threadIdx.x == 0) {
    blk[blockIdx.x * 2 + 0] = ss[0] + ss[1] + ss[2] + ss[3];
    blk[blockIdx.x * 2 + 1] = sc[0] + sc[1] + sc[2] + sc[3];
  }
}

__global__ void reduce2_kernel(const float* __restrict__ blk,
                               float* __restrict__ out) {
  const int lane = threadIdx.x;
  float s = (lane < 32) ? blk[lane * 2 + 0] : 0.0f;
  float c = (lane < 32) ? blk[lane * 2 + 1] : 0.0f;
#pragma unroll
  for (int m = 1; m < 32; m <<= 1) {
    s += __shfl_xor(s, m);
    c += __shfl_xor(c, m);
  }
  if (lane == 0) out[0] = s / fmaxf(c, 1.0f);
}

extern "C" void kernel_launch(void* const* d_in, const int* in_sizes, int n_in,
                              void* d_out, int out_size, void* d_ws,
                              size_t ws_size, hipStream_t stream) {
  const float* inputs = (const float*)d_in[0];
  const int* label = (const int*)d_in[1];
  // d_in[2] = ious (unused by the reference loss)
  const float* lut = (const float*)d_in[3];
  const float* cq = (const float*)d_in[4];
  const float* rel = (const float*)d_in[5];
  float* out = (float*)d_out;
  char* ws = (char*)d_ws;
  if (ws_size < WS_NEED) return;

  unsigned short* in2 = (unsigned short*)(ws + WS_INBF);
  unsigned short* bank3 = (unsigned short*)(ws + WS_BANK);
  float* parts = (float*)(ws + WS_PARTS);
  float* rowlogit = (float*)(ws + WS_RLOGIT);
  float* blk = (float*)(ws + WS_BLK);

  hipFuncSetAttribute((const void*)oim_main_kernel,
                      hipFuncAttributeMaxDynamicSharedMemorySize, 65536);

  prep_kernel<<<dim3(1024), dim3(256), 0, stream>>>(inputs, lut, cq, rel,
                                                    in2, bank3);
  label_logit_kernel<<<dim3(2048), dim3(256), 0, stream>>>(inputs, label, lut,
                                                           cq, rel, rowlogit);
  oim_main_kernel<<<dim3(256), dim3(512), 65536, stream>>>(in2, bank3, parts);
  reduce1_kernel<<<dim3(32), dim3(256), 0, stream>>>(parts, rowlogit, label,
                                                     blk);
  reduce2_kernel<<<dim3(1), dim3(64), 0, stream>>>(blk, out);
}